// Round 1
// 1121.591 us; speedup vs baseline: 1.4050x; 1.4050x over previous
//
#include <hip/hip_runtime.h>
#include <hip/hip_bf16.h>
#include <math.h>

#define BB 4
#define TT 4096
#define DD 1024
#define HH 16
#define DFF 4096
#define KSEL 2048

typedef __attribute__((ext_vector_type(8))) short short8;
typedef __attribute__((ext_vector_type(4))) float f32x4;

__device__ __forceinline__ unsigned short f2bf(float f) {
  union { float f; unsigned int i; } v; v.f = f;
  unsigned int x = v.i;
  unsigned int r = (x + 0x7fffu + ((x >> 16) & 1u)) >> 16;
  return (unsigned short)r;
}
__device__ __forceinline__ float bf2f(unsigned short u) {
  union { unsigned int i; float f; } v; v.i = ((unsigned int)u) << 16; return v.f;
}

// async global->LDS, 16B per lane; lds ptr must be wave-uniform (lane0 = wave base)
__device__ __forceinline__ void gload16(const void* g, void* l) {
  __builtin_amdgcn_global_load_lds(
      (const __attribute__((address_space(1))) void*)g,
      (__attribute__((address_space(3))) void*)l,
      16, 0, 0);
}

// ---------------- f32 -> bf16 conversion (weights) ----------------
__global__ void cvt_kernel(const float* __restrict__ src, unsigned short* __restrict__ dst, int n) {
  int i = (blockIdx.x * 256 + threadIdx.x) * 4;
  if (i + 3 < n) {
    float4 v = *(const float4*)(src + i);
    ushort4 o;
    o.x = f2bf(v.x); o.y = f2bf(v.y); o.z = f2bf(v.z); o.w = f2bf(v.w);
    *(ushort4*)(dst + i) = o;
  }
}

// ---------------- router: f64 dot per token + sigmoid ----------------
__global__ void router_kernel(const float* __restrict__ x,
                              const float* __restrict__ wr,
                              double* __restrict__ dots, float* __restrict__ sig) {
  int token = blockIdx.x * 4 + (threadIdx.x >> 6);
  int lane = threadIdx.x & 63;
  const float* xr = x + (size_t)token * DD;
  double s = 0.0;
  for (int j = lane; j < DD; j += 64)
    s += (double)xr[j] * (double)wr[j];
  for (int o = 32; o > 0; o >>= 1) s += __shfl_down(s, o);
  if (lane == 0) {
    dots[token] = s;
    sig[token] = 1.0f / (1.0f + expf((float)(-s)));
  }
}

// ---------------- rank: count tokens strictly ahead; flag top-k ----------------
__global__ void rank_kernel(const double* __restrict__ dots, int* __restrict__ flags) {
  __shared__ double sd[TT];
  int b = blockIdx.x >> 4;
  int chunk = blockIdx.x & 15;
  const double* drow = dots + (size_t)b * TT;
  for (int j = threadIdx.x; j < TT; j += 256) sd[j] = drow[j];
  __syncthreads();
  int i = chunk * 256 + threadIdx.x;
  double di = sd[i];
  int cnt = 0;
  for (int j = 0; j < TT; ++j) {
    double dj = sd[j];
    cnt += (int)((dj > di) || (dj == di && j < i));
  }
  flags[(size_t)b * TT + i] = (cnt < KSEL) ? 1 : 0;
}

// ---------------- compact: ascending selected GLOBAL indices (b*TT+t) + batch mean ----------------
__global__ void compact_kernel(const int* __restrict__ flags, const float* __restrict__ sig,
                               int* __restrict__ idx, float* __restrict__ means) {
  __shared__ int part[256];
  __shared__ float ssum[256];
  int b = blockIdx.x;
  const int* f = flags + (size_t)b * TT;
  int tid = threadIdx.x;
  int local = 0; float fs = 0.f;
  for (int j = 0; j < 16; ++j) {
    local += f[tid * 16 + j];
    fs += sig[(size_t)b * TT + tid * 16 + j];
  }
  part[tid] = local; ssum[tid] = fs;
  __syncthreads();
  if (tid == 0) {
    int run = 0;
    for (int t = 0; t < 256; ++t) { int c = part[t]; part[t] = run; run += c; }
    float tot = 0.f;
    for (int t = 0; t < 256; ++t) tot += ssum[t];
    means[b] = tot / (float)TT;
  }
  __syncthreads();
  int pos = part[tid];
  for (int j = 0; j < 16; ++j) {
    int t = tid * 16 + j;
    if (f[t]) { idx[(size_t)b * KSEL + pos] = b * TT + t; ++pos; }
  }
}

__global__ void aux_kernel(const float* __restrict__ means, float* __restrict__ out_aux) {
  if (threadIdx.x == 0 && blockIdx.x == 0) {
    float m = 0.f;
    for (int b = 0; b < BB; ++b) m += means[b];
    m *= (1.0f / BB);
    float v = 0.f;
    for (int b = 0; b < BB; ++b) { float d = means[b] - m; v += d * d; }
    v /= (float)(BB - 1);
    *out_aux = v;
  }
}

// ---------------- layernorm: f32 src (optional gather via GLOBAL idx), bf16 dst ----------------
__global__ void ln_kernel(const float* __restrict__ src,
                          const int* __restrict__ idx,
                          const float* __restrict__ scale,
                          const float* __restrict__ bias,
                          unsigned short* __restrict__ dst) {
  int r = blockIdx.x;
  const float* row;
  if (idx) {
    int t = idx[r];                 // global token index b*TT + t
    row = src + (size_t)t * DD;
  } else {
    row = src + (size_t)r * DD;
  }
  __shared__ float red[8];
  __shared__ float mv[2];
  int tid = threadIdx.x;
  float vals[4];
  float s = 0.f, ss = 0.f;
  for (int j = 0; j < 4; ++j) {
    float v = row[tid + 256 * j];
    vals[j] = v; s += v; ss += v * v;
  }
  for (int o = 32; o > 0; o >>= 1) { s += __shfl_down(s, o); ss += __shfl_down(ss, o); }
  int wid = tid >> 6, lane = tid & 63;
  if (lane == 0) { red[wid] = s; red[wid + 4] = ss; }
  __syncthreads();
  if (tid == 0) {
    float a = red[0] + red[1] + red[2] + red[3];
    float q = red[4] + red[5] + red[6] + red[7];
    float mean = a / (float)DD;
    float var = fmaxf(q / (float)DD - mean * mean, 0.f);
    mv[0] = mean; mv[1] = rsqrtf(var + 1e-5f);
  }
  __syncthreads();
  float mean = mv[0], rst = mv[1];
  unsigned short* drow = dst + (size_t)r * DD;
  for (int j = 0; j < 4; ++j) {
    int c = tid + 256 * j;
    float v = (vals[j] - mean) * rst * scale[c] + bias[c];
    drow[c] = f2bf(v);
  }
}

// ---------------- BT-form MFMA GEMM (m97 structure): acc = A[M,K] * W[N,K]^T ----------------
// linear LDS [128][32] + global_load_lds width 16, 2 barriers per K-step.
// EPI 0: Cb[row*N+col] = bf16(acc)                          (qkv)
// EPI 1: fout[row*DD+col] = xin[gidx[row]*DD+col] + acc     (x1 = x_sel + attn, f32)
// EPI 2: fout[gidx[row]*DD+col] = xin[row*DD+col] + acc     (scatter out = x1 + ffn, f32)
template <int EPI>
__launch_bounds__(256, 2)
__global__ void gemm_bt(const unsigned short* __restrict__ A,
                        const unsigned short* __restrict__ W,
                        int K, int N,
                        unsigned short* __restrict__ Cb,
                        const int* __restrict__ idx,
                        const float* __restrict__ xin,
                        float* __restrict__ fout) {
  __shared__ unsigned short As[128 * 32];
  __shared__ unsigned short Bs[128 * 32];
  int bm = blockIdx.x, bn = blockIdx.y;
  int tid = threadIdx.x;
  int wid = tid >> 6, lane = tid & 63;
  int quad = lane >> 4, l15 = lane & 15;
  int wm = (wid >> 1) * 64, wn = (wid & 1) * 64;

  f32x4 acc[4][4] = {};
  const int arow0 = bm * 128, brow0 = bn * 128;
  int srow = tid >> 2;
  int scol = (tid & 3) * 8;
  const unsigned short* Ag = A + (size_t)(arow0 + srow) * K + scol;
  const unsigned short* Wg = W + (size_t)(brow0 + srow) * K + scol;
  // wave-uniform LDS staging base: wave w covers rows 16w..16w+15 (1024B)
  unsigned short* AsW = As + (size_t)(tid & 192) * 8;
  unsigned short* BsW = Bs + (size_t)(tid & 192) * 8;

  for (int k0 = 0; k0 < K; k0 += 32) {
    __syncthreads();  // prior reads drained before overwrite
    gload16(Ag + k0, AsW);
    gload16(Ag + (size_t)64 * K + k0, AsW + 2048);
    gload16(Wg + k0, BsW);
    gload16(Wg + (size_t)64 * K + k0, BsW + 2048);
    __syncthreads();  // vmcnt(0) drain -> staged data visible
    short8 af[4], bfr[4];
    for (int t = 0; t < 4; ++t) af[t]  = *(const short8*)&As[(wm + t * 16 + l15) * 32 + quad * 8];
    for (int t = 0; t < 4; ++t) bfr[t] = *(const short8*)&Bs[(wn + t * 16 + l15) * 32 + quad * 8];
    for (int i = 0; i < 4; ++i)
      for (int j = 0; j < 4; ++j)
        acc[i][j] = __builtin_amdgcn_mfma_f32_16x16x32_bf16(af[i], bfr[j], acc[i][j], 0, 0, 0);
  }

  for (int i = 0; i < 4; ++i)
    for (int j = 0; j < 4; ++j)
      for (int r = 0; r < 4; ++r) {
        int row = arow0 + wm + i * 16 + quad * 4 + r;
        int col = brow0 + wn + j * 16 + l15;
        float v = acc[i][j][r];
        if (EPI == 0) {
          Cb[(size_t)row * N + col] = f2bf(v);
        } else if (EPI == 1) {
          int t = idx[row];
          fout[(size_t)row * DD + col] = xin[(size_t)t * DD + col] + v;
        } else {
          int t = idx[row];
          fout[(size_t)t * DD + col] = xin[(size_t)row * DD + col] + v;
        }
      }
}

// ---------------- dual-B GEMM for SwiGLU (m97 structure): g = silu(A*W1^T) * (A*W2^T) ----------------
__launch_bounds__(256, 2)
__global__ void gemm_dual(const unsigned short* __restrict__ A,
                          const unsigned short* __restrict__ W1,
                          const unsigned short* __restrict__ W2,
                          unsigned short* __restrict__ G,
                          int K, int N) {
  __shared__ unsigned short As[128 * 32];
  __shared__ unsigned short B1s[128 * 32];
  __shared__ unsigned short B2s[128 * 32];
  int bm = blockIdx.x, bn = blockIdx.y;
  int tid = threadIdx.x;
  int wid = tid >> 6, lane = tid & 63;
  int quad = lane >> 4, l15 = lane & 15;
  int wm = (wid >> 1) * 64, wn = (wid & 1) * 64;

  f32x4 acc1[4][4] = {};
  f32x4 acc2[4][4] = {};
  const int arow0 = bm * 128, brow0 = bn * 128;
  int srow = tid >> 2;
  int scol = (tid & 3) * 8;
  const unsigned short* Ag  = A  + (size_t)(arow0 + srow) * K + scol;
  const unsigned short* W1g = W1 + (size_t)(brow0 + srow) * K + scol;
  const unsigned short* W2g = W2 + (size_t)(brow0 + srow) * K + scol;
  unsigned short* AsW  = As  + (size_t)(tid & 192) * 8;
  unsigned short* B1sW = B1s + (size_t)(tid & 192) * 8;
  unsigned short* B2sW = B2s + (size_t)(tid & 192) * 8;

  for (int k0 = 0; k0 < K; k0 += 32) {
    __syncthreads();
    gload16(Ag + k0, AsW);
    gload16(Ag + (size_t)64 * K + k0, AsW + 2048);
    gload16(W1g + k0, B1sW);
    gload16(W1g + (size_t)64 * K + k0, B1sW + 2048);
    gload16(W2g + k0, B2sW);
    gload16(W2g + (size_t)64 * K + k0, B2sW + 2048);
    __syncthreads();
    short8 af[4], b1f[4], b2f[4];
    for (int t = 0; t < 4; ++t) af[t]  = *(const short8*)&As[(wm + t * 16 + l15) * 32 + quad * 8];
    for (int t = 0; t < 4; ++t) b1f[t] = *(const short8*)&B1s[(wn + t * 16 + l15) * 32 + quad * 8];
    for (int t = 0; t < 4; ++t) b2f[t] = *(const short8*)&B2s[(wn + t * 16 + l15) * 32 + quad * 8];
    for (int i = 0; i < 4; ++i)
      for (int j = 0; j < 4; ++j) {
        acc1[i][j] = __builtin_amdgcn_mfma_f32_16x16x32_bf16(af[i], b1f[j], acc1[i][j], 0, 0, 0);
        acc2[i][j] = __builtin_amdgcn_mfma_f32_16x16x32_bf16(af[i], b2f[j], acc2[i][j], 0, 0, 0);
      }
  }

  for (int i = 0; i < 4; ++i)
    for (int j = 0; j < 4; ++j)
      for (int r = 0; r < 4; ++r) {
        int row = arow0 + wm + i * 16 + quad * 4 + r;
        int col = brow0 + wn + j * 16 + l15;
        float u1 = acc1[i][j][r];
        float u2 = acc2[i][j][r];
        float sg = u1 / (1.0f + expf(-u1));  // silu
        G[(size_t)row * N + col] = f2bf(sg * u2);
      }
}

// ---------------- flash attention over selected tokens (batch via blockIdx.z) ----------------
__launch_bounds__(256)
__global__ void attn_kernel(const unsigned short* __restrict__ qkv_all,
                            unsigned short* __restrict__ obuf_all) {
  int qb = blockIdx.x;   // 0..31
  int h = blockIdx.y;    // 0..15
  const unsigned short* qkv = qkv_all + (size_t)blockIdx.z * KSEL * 3 * DD;
  unsigned short* obuf = obuf_all + (size_t)blockIdx.z * KSEL * DD;
  int tid = threadIdx.x, wid = tid >> 6, lane = tid & 63;
  int quad = lane >> 4, l15 = lane & 15;

  __shared__ unsigned short Ks[32][72];
  __shared__ unsigned short Vt[64][40];
  __shared__ unsigned short Ps[4][16][40];

  int qrow = qb * 64 + wid * 16 + l15;
  const unsigned short* qptr = qkv + (size_t)qrow * (3 * DD) + h * 64;
  short8 aq0 = *(const short8*)(qptr + quad * 8);
  short8 aq1 = *(const short8*)(qptr + 32 + quad * 8);

  float m_r[4], l_r[4];
  f32x4 o_acc[4] = {};
  for (int r = 0; r < 4; ++r) { m_r[r] = -1e30f; l_r[r] = 0.f; }

  int skey = tid >> 3;
  int scol = (tid & 7) * 8;
  const unsigned short* kbase = qkv + DD + h * 64;
  const unsigned short* vbase = qkv + 2 * DD + h * 64;

  for (int kt = 0; kt < KSEL / 32; ++kt) {
    int key0 = kt * 32;
    uint4 kv = *(const uint4*)(kbase + (size_t)(key0 + skey) * (3 * DD) + scol);
    uint4 vv = *(const uint4*)(vbase + (size_t)(key0 + skey) * (3 * DD) + scol);
    __syncthreads();
    *(uint4*)&Ks[skey][scol] = kv;
    const unsigned short* vp = (const unsigned short*)&vv;
    for (int j = 0; j < 8; ++j) Vt[scol + j][skey] = vp[j];
    __syncthreads();

    f32x4 s0 = {0.f, 0.f, 0.f, 0.f}, s1 = {0.f, 0.f, 0.f, 0.f};
    short8 k00 = *(const short8*)&Ks[l15][quad * 8];
    short8 k01 = *(const short8*)&Ks[l15][32 + quad * 8];
    short8 k10 = *(const short8*)&Ks[16 + l15][quad * 8];
    short8 k11 = *(const short8*)&Ks[16 + l15][32 + quad * 8];
    s0 = __builtin_amdgcn_mfma_f32_16x16x32_bf16(aq0, k00, s0, 0, 0, 0);
    s0 = __builtin_amdgcn_mfma_f32_16x16x32_bf16(aq1, k01, s0, 0, 0, 0);
    s1 = __builtin_amdgcn_mfma_f32_16x16x32_bf16(aq0, k10, s1, 0, 0, 0);
    s1 = __builtin_amdgcn_mfma_f32_16x16x32_bf16(aq1, k11, s1, 0, 0, 0);

    float p0[4], p1[4], alpha[4];
    for (int r = 0; r < 4; ++r) {
      float s0v = s0[r] * 0.125f, s1v = s1[r] * 0.125f;
      float mx = fmaxf(s0v, s1v);
      for (int o = 1; o < 16; o <<= 1) mx = fmaxf(mx, __shfl_xor(mx, o));
      float mnew = fmaxf(m_r[r], mx);
      alpha[r] = expf(m_r[r] - mnew);
      p0[r] = expf(s0v - mnew);
      p1[r] = expf(s1v - mnew);
      float ls = p0[r] + p1[r];
      for (int o = 1; o < 16; o <<= 1) ls += __shfl_xor(ls, o);
      l_r[r] = l_r[r] * alpha[r] + ls;
      m_r[r] = mnew;
    }
    for (int dt = 0; dt < 4; ++dt)
      for (int r = 0; r < 4; ++r) o_acc[dt][r] *= alpha[r];

    for (int r = 0; r < 4; ++r) {
      Ps[wid][quad * 4 + r][l15] = f2bf(p0[r]);
      Ps[wid][quad * 4 + r][16 + l15] = f2bf(p1[r]);
    }
    short8 ap = *(const short8*)&Ps[wid][l15][quad * 8];
    for (int dt = 0; dt < 4; ++dt) {
      short8 vf = *(const short8*)&Vt[dt * 16 + l15][quad * 8];
      o_acc[dt] = __builtin_amdgcn_mfma_f32_16x16x32_bf16(ap, vf, o_acc[dt], 0, 0, 0);
    }
  }

  int orow = qb * 64 + wid * 16 + quad * 4;
  unsigned short* op = obuf + h * 64;
  for (int dt = 0; dt < 4; ++dt)
    for (int r = 0; r < 4; ++r) {
      float v = o_acc[dt][r] / l_r[r];
      op[(size_t)(orow + r) * DD + dt * 16 + l15] = f2bf(v);
    }
}

// ---------------- launch: batched across B with ws_size-adaptive chunking ----------------
extern "C" void kernel_launch(void* const* d_in, const int* in_sizes, int n_in,
                              void* d_out, int out_size, void* d_ws, size_t ws_size,
                              hipStream_t stream) {
  const float* x    = (const float*)d_in[0];
  const float* wr   = (const float*)d_in[1];
  const float* ln1s = (const float*)d_in[2];
  const float* ln1b = (const float*)d_in[3];
  const float* ln2s = (const float*)d_in[4];
  const float* ln2b = (const float*)d_in[5];
  const float* wqkv = (const float*)d_in[6];
  const float* wout = (const float*)d_in[7];
  const float* w1   = (const float*)d_in[8];
  const float* w2   = (const float*)d_in[9];
  const float* w3   = (const float*)d_in[10];
  float* out = (float*)d_out;
  char* ws = (char*)d_ws;

  // control region [0, 1 MiB)
  double* dots  = (double*)(ws + 0);        // 128 KiB
  float*  sig   = (float*)(ws + 131072);    // 64 KiB
  int*    flags = (int*)(ws + 196608);      // 64 KiB
  int*    idx   = (int*)(ws + 262144);      // 32 KiB (global token indices)
  float*  means = (float*)(ws + 294912);    // 16 B
  // bf16 weight copies [1 MiB, 33 MiB)
  unsigned short* wqkv_h = (unsigned short*)(ws + ((size_t)1 << 20));   // 6 MiB
  unsigned short* wout_h = (unsigned short*)(ws + ((size_t)7 << 20));   // 2 MiB
  unsigned short* w1_h   = (unsigned short*)(ws + ((size_t)9 << 20));   // 8 MiB
  unsigned short* w2_h   = (unsigned short*)(ws + ((size_t)17 << 20));  // 8 MiB
  unsigned short* w3_h   = (unsigned short*)(ws + ((size_t)25 << 20));  // 8 MiB
  const size_t base = (size_t)33 << 20;

  // out = x (pass-through for unselected tokens), f32, 64 MiB
  hipMemcpyAsync(out, x, (size_t)BB * TT * DD * sizeof(float),
                 hipMemcpyDeviceToDevice, stream);

  // weight conversions f32 -> bf16
  cvt_kernel<<<dim3(3 * DD * DD / 1024), dim3(256), 0, stream>>>(wqkv, wqkv_h, 3 * DD * DD);
  cvt_kernel<<<dim3(DD * DD / 1024), dim3(256), 0, stream>>>(wout, wout_h, DD * DD);
  cvt_kernel<<<dim3(DFF * DD / 1024), dim3(256), 0, stream>>>(w1, w1_h, DFF * DD);
  cvt_kernel<<<dim3(DFF * DD / 1024), dim3(256), 0, stream>>>(w2, w2_h, DFF * DD);
  cvt_kernel<<<dim3(DD * DFF / 1024), dim3(256), 0, stream>>>(w3, w3_h, DD * DFF);

  router_kernel<<<dim3(BB * TT / 4), dim3(256), 0, stream>>>(x, wr, dots, sig);
  rank_kernel<<<dim3(BB * 16), dim3(256), 0, stream>>>(dots, flags);
  compact_kernel<<<dim3(BB), dim3(256), 0, stream>>>(flags, sig, idx, means);
  aux_kernel<<<dim3(1), dim3(64), 0, stream>>>(means, out + (size_t)BB * TT * DD);

  // per-row buffer bytes: x1 4096 + norm 2048 + max(qkv 6144 + obuf 2048, gbuf 8192) = 14336
  int cb = 4;  // batches per chunk
  while (cb > 1 && base + (size_t)cb * KSEL * 14336 > ws_size) cb >>= 1;

  for (int c0 = 0; c0 < BB; c0 += cb) {
    const int R = cb * KSEL;  // rows in this chunk
    const int* gidx = idx + (size_t)c0 * KSEL;
    float*          x1    = (float*)(ws + base);
    unsigned short* normb = (unsigned short*)(ws + base + (size_t)R * 4096);
    unsigned short* qkvb  = (unsigned short*)(ws + base + (size_t)R * 6144);
    unsigned short* obufb = (unsigned short*)(ws + base + (size_t)R * 12288);
    unsigned short* gbuf  = qkvb;  // overlays dead qkv+obuf (R*8192 <= R*6144 + R*2048)

    // ln1 on gathered selected tokens -> bf16
    ln_kernel<<<dim3(R), dim3(256), 0, stream>>>(x, gidx, ln1s, ln1b, normb);

    // qkv = normed @ w_qkv^T  (R x 3072, K=1024) -> bf16
    gemm_bt<0><<<dim3(R / 128, 3 * DD / 128), dim3(256), 0, stream>>>(
        normb, wqkv_h, DD, 3 * DD, qkvb, nullptr, nullptr, nullptr);

    // attention -> bf16 obuf (per-batch via blockIdx.z)
    attn_kernel<<<dim3(KSEL / 64, HH, cb), dim3(256), 0, stream>>>(qkvb, obufb);

    // x1 = x_sel + o @ w_out^T  -> f32
    gemm_bt<1><<<dim3(R / 128, DD / 128), dim3(256), 0, stream>>>(
        obufb, wout_h, DD, DD, nullptr, gidx, x, x1);

    // ln2 -> bf16
    ln_kernel<<<dim3(R), dim3(256), 0, stream>>>(x1, nullptr, ln2s, ln2b, normb);

    // g = silu(h@w1^T) * (h@w2^T)  (R x 4096, K=1024) -> bf16
    gemm_dual<<<dim3(R / 128, DFF / 128), dim3(256), 0, stream>>>(
        normb, w1_h, w2_h, gbuf, DD, DFF);

    // out[gidx, :] = x1 + g @ w3^T  (K=4096) -> f32 scatter
    gemm_bt<2><<<dim3(R / 128, DD / 128), dim3(256), 0, stream>>>(
        gbuf, w3_h, DFF, DD, nullptr, gidx, x1, out);
  }
}

// Round 2
// 947.170 us; speedup vs baseline: 1.6637x; 1.1842x over previous
//
#include <hip/hip_runtime.h>
#include <hip/hip_bf16.h>
#include <math.h>

#define BB 4
#define TT 4096
#define DD 1024
#define HH 16
#define DFF 4096
#define KSEL 2048

typedef __attribute__((ext_vector_type(8))) short short8;
typedef __attribute__((ext_vector_type(4))) float f32x4;

__device__ __forceinline__ unsigned short f2bf(float f) {
  union { float f; unsigned int i; } v; v.f = f;
  unsigned int x = v.i;
  unsigned int r = (x + 0x7fffu + ((x >> 16) & 1u)) >> 16;
  return (unsigned short)r;
}
__device__ __forceinline__ float bf2f(unsigned short u) {
  union { unsigned int i; float f; } v; v.i = ((unsigned int)u) << 16; return v.f;
}

// async global->LDS, 16B per lane; lds ptr must be wave-uniform (lane0 = wave base)
__device__ __forceinline__ void gload16(const void* g, void* l) {
  __builtin_amdgcn_global_load_lds(
      (const __attribute__((address_space(1))) void*)g,
      (__attribute__((address_space(3))) void*)l,
      16, 0, 0);
}

// ---------------- f32 -> bf16 conversion (weights) ----------------
__global__ void cvt_kernel(const float* __restrict__ src, unsigned short* __restrict__ dst, int n) {
  int i = (blockIdx.x * 256 + threadIdx.x) * 4;
  if (i + 3 < n) {
    float4 v = *(const float4*)(src + i);
    ushort4 o;
    o.x = f2bf(v.x); o.y = f2bf(v.y); o.z = f2bf(v.z); o.w = f2bf(v.w);
    *(ushort4*)(dst + i) = o;
  }
}

// ---------------- router: f64 dot per token + sigmoid ----------------
__global__ void router_kernel(const float* __restrict__ x,
                              const float* __restrict__ wr,
                              double* __restrict__ dots, float* __restrict__ sig) {
  int token = blockIdx.x * 4 + (threadIdx.x >> 6);
  int lane = threadIdx.x & 63;
  const float* xr = x + (size_t)token * DD;
  double s = 0.0;
  for (int j = lane; j < DD; j += 64)
    s += (double)xr[j] * (double)wr[j];
  for (int o = 32; o > 0; o >>= 1) s += __shfl_down(s, o);
  if (lane == 0) {
    dots[token] = s;
    sig[token] = 1.0f / (1.0f + expf((float)(-s)));
  }
}

// ---------------- rank: count tokens strictly ahead; flag top-k ----------------
__global__ void rank_kernel(const double* __restrict__ dots, int* __restrict__ flags) {
  __shared__ double sd[TT];
  int b = blockIdx.x >> 4;
  int chunk = blockIdx.x & 15;
  const double* drow = dots + (size_t)b * TT;
  for (int j = threadIdx.x; j < TT; j += 256) sd[j] = drow[j];
  __syncthreads();
  int i = chunk * 256 + threadIdx.x;
  double di = sd[i];
  int cnt = 0;
  for (int j = 0; j < TT; ++j) {
    double dj = sd[j];
    cnt += (int)((dj > di) || (dj == di && j < i));
  }
  flags[(size_t)b * TT + i] = (cnt < KSEL) ? 1 : 0;
}

// ---------------- compact: ascending selected GLOBAL indices (b*TT+t) + batch mean ----------------
__global__ void compact_kernel(const int* __restrict__ flags, const float* __restrict__ sig,
                               int* __restrict__ idx, float* __restrict__ means) {
  __shared__ int part[256];
  __shared__ float ssum[256];
  int b = blockIdx.x;
  const int* f = flags + (size_t)b * TT;
  int tid = threadIdx.x;
  int local = 0; float fs = 0.f;
  for (int j = 0; j < 16; ++j) {
    local += f[tid * 16 + j];
    fs += sig[(size_t)b * TT + tid * 16 + j];
  }
  part[tid] = local; ssum[tid] = fs;
  __syncthreads();
  if (tid == 0) {
    int run = 0;
    for (int t = 0; t < 256; ++t) { int c = part[t]; part[t] = run; run += c; }
    float tot = 0.f;
    for (int t = 0; t < 256; ++t) tot += ssum[t];
    means[b] = tot / (float)TT;
  }
  __syncthreads();
  int pos = part[tid];
  for (int j = 0; j < 16; ++j) {
    int t = tid * 16 + j;
    if (f[t]) { idx[(size_t)b * KSEL + pos] = b * TT + t; ++pos; }
  }
}

__global__ void aux_kernel(const float* __restrict__ means, float* __restrict__ out_aux) {
  if (threadIdx.x == 0 && blockIdx.x == 0) {
    float m = 0.f;
    for (int b = 0; b < BB; ++b) m += means[b];
    m *= (1.0f / BB);
    float v = 0.f;
    for (int b = 0; b < BB; ++b) { float d = means[b] - m; v += d * d; }
    v /= (float)(BB - 1);
    *out_aux = v;
  }
}

// ---------------- layernorm: f32 src (optional gather via GLOBAL idx), bf16 dst ----------------
__global__ void ln_kernel(const float* __restrict__ src,
                          const int* __restrict__ idx,
                          const float* __restrict__ scale,
                          const float* __restrict__ bias,
                          unsigned short* __restrict__ dst) {
  int r = blockIdx.x;
  const float* row;
  if (idx) {
    int t = idx[r];                 // global token index b*TT + t
    row = src + (size_t)t * DD;
  } else {
    row = src + (size_t)r * DD;
  }
  __shared__ float red[8];
  __shared__ float mv[2];
  int tid = threadIdx.x;
  float vals[4];
  float s = 0.f, ss = 0.f;
  for (int j = 0; j < 4; ++j) {
    float v = row[tid + 256 * j];
    vals[j] = v; s += v; ss += v * v;
  }
  for (int o = 32; o > 0; o >>= 1) { s += __shfl_down(s, o); ss += __shfl_down(ss, o); }
  int wid = tid >> 6, lane = tid & 63;
  if (lane == 0) { red[wid] = s; red[wid + 4] = ss; }
  __syncthreads();
  if (tid == 0) {
    float a = red[0] + red[1] + red[2] + red[3];
    float q = red[4] + red[5] + red[6] + red[7];
    float mean = a / (float)DD;
    float var = fmaxf(q / (float)DD - mean * mean, 0.f);
    mv[0] = mean; mv[1] = rsqrtf(var + 1e-5f);
  }
  __syncthreads();
  float mean = mv[0], rst = mv[1];
  unsigned short* drow = dst + (size_t)r * DD;
  for (int j = 0; j < 4; ++j) {
    int c = tid + 256 * j;
    float v = (vals[j] - mean) * rst * scale[c] + bias[c];
    drow[c] = f2bf(v);
  }
}

// ---------------- BT-form MFMA GEMM (m97 structure): acc = A[M,K] * W[N,K]^T ----------------
// linear LDS [128][32] + global_load_lds width 16, 2 barriers per K-step.
// EPI 0: Cb[row*N+col] = bf16(acc)                          (qkv)
// EPI 1: fout[row*DD+col] = xin[gidx[row]*DD+col] + acc     (x1 = x_sel + attn, f32)
// EPI 2: fout[gidx[row]*DD+col] = xin[row*DD+col] + acc     (scatter out = x1 + ffn, f32)
template <int EPI>
__launch_bounds__(256, 2)
__global__ void gemm_bt(const unsigned short* __restrict__ A,
                        const unsigned short* __restrict__ W,
                        int K, int N,
                        unsigned short* __restrict__ Cb,
                        const int* __restrict__ idx,
                        const float* __restrict__ xin,
                        float* __restrict__ fout) {
  __shared__ unsigned short As[128 * 32];
  __shared__ unsigned short Bs[128 * 32];
  int bm = blockIdx.x, bn = blockIdx.y;
  int tid = threadIdx.x;
  int wid = tid >> 6, lane = tid & 63;
  int quad = lane >> 4, l15 = lane & 15;
  int wm = (wid >> 1) * 64, wn = (wid & 1) * 64;

  f32x4 acc[4][4] = {};
  const int arow0 = bm * 128, brow0 = bn * 128;
  int srow = tid >> 2;
  int scol = (tid & 3) * 8;
  const unsigned short* Ag = A + (size_t)(arow0 + srow) * K + scol;
  const unsigned short* Wg = W + (size_t)(brow0 + srow) * K + scol;
  // wave-uniform LDS staging base: wave w covers rows 16w..16w+15 (1024B)
  unsigned short* AsW = As + (size_t)(tid & 192) * 8;
  unsigned short* BsW = Bs + (size_t)(tid & 192) * 8;

  for (int k0 = 0; k0 < K; k0 += 32) {
    __syncthreads();  // prior reads drained before overwrite
    gload16(Ag + k0, AsW);
    gload16(Ag + (size_t)64 * K + k0, AsW + 2048);
    gload16(Wg + k0, BsW);
    gload16(Wg + (size_t)64 * K + k0, BsW + 2048);
    __syncthreads();  // vmcnt(0) drain -> staged data visible
    short8 af[4], bfr[4];
    for (int t = 0; t < 4; ++t) af[t]  = *(const short8*)&As[(wm + t * 16 + l15) * 32 + quad * 8];
    for (int t = 0; t < 4; ++t) bfr[t] = *(const short8*)&Bs[(wn + t * 16 + l15) * 32 + quad * 8];
    for (int i = 0; i < 4; ++i)
      for (int j = 0; j < 4; ++j)
        acc[i][j] = __builtin_amdgcn_mfma_f32_16x16x32_bf16(af[i], bfr[j], acc[i][j], 0, 0, 0);
  }

  for (int i = 0; i < 4; ++i)
    for (int j = 0; j < 4; ++j)
      for (int r = 0; r < 4; ++r) {
        int row = arow0 + wm + i * 16 + quad * 4 + r;
        int col = brow0 + wn + j * 16 + l15;
        float v = acc[i][j][r];
        if (EPI == 0) {
          Cb[(size_t)row * N + col] = f2bf(v);
        } else if (EPI == 1) {
          int t = idx[row];
          fout[(size_t)row * DD + col] = xin[(size_t)t * DD + col] + v;
        } else {
          int t = idx[row];
          fout[(size_t)t * DD + col] = xin[(size_t)row * DD + col] + v;
        }
      }
}

// ---------------- dual-B GEMM for SwiGLU (m97 structure): g = silu(A*W1^T) * (A*W2^T) ----------------
__launch_bounds__(256, 2)
__global__ void gemm_dual(const unsigned short* __restrict__ A,
                          const unsigned short* __restrict__ W1,
                          const unsigned short* __restrict__ W2,
                          unsigned short* __restrict__ G,
                          int K, int N) {
  __shared__ unsigned short As[128 * 32];
  __shared__ unsigned short B1s[128 * 32];
  __shared__ unsigned short B2s[128 * 32];
  int bm = blockIdx.x, bn = blockIdx.y;
  int tid = threadIdx.x;
  int wid = tid >> 6, lane = tid & 63;
  int quad = lane >> 4, l15 = lane & 15;
  int wm = (wid >> 1) * 64, wn = (wid & 1) * 64;

  f32x4 acc1[4][4] = {};
  f32x4 acc2[4][4] = {};
  const int arow0 = bm * 128, brow0 = bn * 128;
  int srow = tid >> 2;
  int scol = (tid & 3) * 8;
  const unsigned short* Ag  = A  + (size_t)(arow0 + srow) * K + scol;
  const unsigned short* W1g = W1 + (size_t)(brow0 + srow) * K + scol;
  const unsigned short* W2g = W2 + (size_t)(brow0 + srow) * K + scol;
  unsigned short* AsW  = As  + (size_t)(tid & 192) * 8;
  unsigned short* B1sW = B1s + (size_t)(tid & 192) * 8;
  unsigned short* B2sW = B2s + (size_t)(tid & 192) * 8;

  for (int k0 = 0; k0 < K; k0 += 32) {
    __syncthreads();
    gload16(Ag + k0, AsW);
    gload16(Ag + (size_t)64 * K + k0, AsW + 2048);
    gload16(W1g + k0, B1sW);
    gload16(W1g + (size_t)64 * K + k0, B1sW + 2048);
    gload16(W2g + k0, B2sW);
    gload16(W2g + (size_t)64 * K + k0, B2sW + 2048);
    __syncthreads();
    short8 af[4], b1f[4], b2f[4];
    for (int t = 0; t < 4; ++t) af[t]  = *(const short8*)&As[(wm + t * 16 + l15) * 32 + quad * 8];
    for (int t = 0; t < 4; ++t) b1f[t] = *(const short8*)&B1s[(wn + t * 16 + l15) * 32 + quad * 8];
    for (int t = 0; t < 4; ++t) b2f[t] = *(const short8*)&B2s[(wn + t * 16 + l15) * 32 + quad * 8];
    for (int i = 0; i < 4; ++i)
      for (int j = 0; j < 4; ++j) {
        acc1[i][j] = __builtin_amdgcn_mfma_f32_16x16x32_bf16(af[i], b1f[j], acc1[i][j], 0, 0, 0);
        acc2[i][j] = __builtin_amdgcn_mfma_f32_16x16x32_bf16(af[i], b2f[j], acc2[i][j], 0, 0, 0);
      }
  }

  for (int i = 0; i < 4; ++i)
    for (int j = 0; j < 4; ++j)
      for (int r = 0; r < 4; ++r) {
        int row = arow0 + wm + i * 16 + quad * 4 + r;
        int col = brow0 + wn + j * 16 + l15;
        float u1 = acc1[i][j][r];
        float u2 = acc2[i][j][r];
        float sg = u1 / (1.0f + __expf(-u1));  // silu (native exp)
        G[(size_t)row * N + col] = f2bf(sg * u2);
      }
}

// ---------------- flash attention over selected tokens (batch via blockIdx.z) ----------------
// KVBLK=64; native __expf softmax; conflict-free LDS strides (68 shorts, odd dword multiplier)
__launch_bounds__(256)
__global__ void attn_kernel(const unsigned short* __restrict__ qkv_all,
                            unsigned short* __restrict__ obuf_all) {
  int qb = blockIdx.x;   // 0..31
  int h = blockIdx.y;    // 0..15
  const unsigned short* qkv = qkv_all + (size_t)blockIdx.z * KSEL * 3 * DD;
  unsigned short* obuf = obuf_all + (size_t)blockIdx.z * KSEL * DD;
  int tid = threadIdx.x, wid = tid >> 6, lane = tid & 63;
  int quad = lane >> 4, l15 = lane & 15;

  __shared__ unsigned short Ks[64][68];      // K rows x 64 dims (pad 68: bank = 2*row + ...)
  __shared__ unsigned short Vt[64][68];      // V^T: d rows x 64 keys
  __shared__ unsigned short Ps[4][16][68];   // per-warp P: 16 q-rows x 64 keys

  int qrow = qb * 64 + wid * 16 + l15;
  const unsigned short* qptr = qkv + (size_t)qrow * (3 * DD) + h * 64;
  short8 aq0 = *(const short8*)(qptr + quad * 8);
  short8 aq1 = *(const short8*)(qptr + 32 + quad * 8);

  float m_r[4], l_r[4];
  f32x4 o_acc[4] = {};
  for (int r = 0; r < 4; ++r) { m_r[r] = -1e30f; l_r[r] = 0.f; }

  int skey = tid >> 2;          // 0..63
  int scol = (tid & 3) * 16;    // 0,16,32,48
  const unsigned short* kbase = qkv + DD + h * 64;
  const unsigned short* vbase = qkv + 2 * DD + h * 64;

  for (int kt = 0; kt < KSEL / 64; ++kt) {
    int key0 = kt * 64;
    const unsigned short* krow = kbase + (size_t)(key0 + skey) * (3 * DD) + scol;
    const unsigned short* vrow = vbase + (size_t)(key0 + skey) * (3 * DD) + scol;
    uint4 k0 = *(const uint4*)(krow);
    uint4 k1 = *(const uint4*)(krow + 8);
    uint4 v0 = *(const uint4*)(vrow);
    uint4 v1 = *(const uint4*)(vrow + 8);
    __syncthreads();
    *(uint4*)&Ks[skey][scol] = k0;
    *(uint4*)&Ks[skey][scol + 8] = k1;
    {
      const unsigned short* vp0 = (const unsigned short*)&v0;
      const unsigned short* vp1 = (const unsigned short*)&v1;
#pragma unroll
      for (int j = 0; j < 8; ++j) Vt[scol + j][skey] = vp0[j];
#pragma unroll
      for (int j = 0; j < 8; ++j) Vt[scol + 8 + j][skey] = vp1[j];
    }
    __syncthreads();

    // QK^T: S[q][key], q = wid*16+quad*4+r, key = t*16+l15
    f32x4 s[4];
#pragma unroll
    for (int t = 0; t < 4; ++t) {
      f32x4 z = {0.f, 0.f, 0.f, 0.f};
      short8 ka = *(const short8*)&Ks[t * 16 + l15][quad * 8];
      short8 kb = *(const short8*)&Ks[t * 16 + l15][32 + quad * 8];
      z = __builtin_amdgcn_mfma_f32_16x16x32_bf16(aq0, ka, z, 0, 0, 0);
      z = __builtin_amdgcn_mfma_f32_16x16x32_bf16(aq1, kb, z, 0, 0, 0);
      s[t] = z;
    }

    // online softmax (native exp)
    float p[4][4], alpha[4];
#pragma unroll
    for (int r = 0; r < 4; ++r) {
      float sv0 = s[0][r] * 0.125f, sv1 = s[1][r] * 0.125f;
      float sv2 = s[2][r] * 0.125f, sv3 = s[3][r] * 0.125f;
      float mx = fmaxf(fmaxf(sv0, sv1), fmaxf(sv2, sv3));
#pragma unroll
      for (int o = 1; o < 16; o <<= 1) mx = fmaxf(mx, __shfl_xor(mx, o));
      float mnew = fmaxf(m_r[r], mx);
      alpha[r] = __expf(m_r[r] - mnew);
      float p0 = __expf(sv0 - mnew), p1 = __expf(sv1 - mnew);
      float p2 = __expf(sv2 - mnew), p3 = __expf(sv3 - mnew);
      p[0][r] = p0; p[1][r] = p1; p[2][r] = p2; p[3][r] = p3;
      float ls = (p0 + p1) + (p2 + p3);
#pragma unroll
      for (int o = 1; o < 16; o <<= 1) ls += __shfl_xor(ls, o);
      l_r[r] = l_r[r] * alpha[r] + ls;
      m_r[r] = mnew;
    }
#pragma unroll
    for (int dt = 0; dt < 4; ++dt)
#pragma unroll
      for (int r = 0; r < 4; ++r) o_acc[dt][r] *= alpha[r];

    // P -> LDS (conflict-free: bank = 8*quad + 2*r + 8*t + (l15>>1))
#pragma unroll
    for (int t = 0; t < 4; ++t)
#pragma unroll
      for (int r = 0; r < 4; ++r)
        Ps[wid][quad * 4 + r][t * 16 + l15] = f2bf(p[t][r]);

    short8 ap0 = *(const short8*)&Ps[wid][l15][quad * 8];
    short8 ap1 = *(const short8*)&Ps[wid][l15][32 + quad * 8];
#pragma unroll
    for (int dt = 0; dt < 4; ++dt) {
      short8 vf0 = *(const short8*)&Vt[dt * 16 + l15][quad * 8];
      short8 vf1 = *(const short8*)&Vt[dt * 16 + l15][32 + quad * 8];
      o_acc[dt] = __builtin_amdgcn_mfma_f32_16x16x32_bf16(ap0, vf0, o_acc[dt], 0, 0, 0);
      o_acc[dt] = __builtin_amdgcn_mfma_f32_16x16x32_bf16(ap1, vf1, o_acc[dt], 0, 0, 0);
    }
  }

  float rl[4];
#pragma unroll
  for (int r = 0; r < 4; ++r) rl[r] = 1.0f / l_r[r];
  int orow = qb * 64 + wid * 16 + quad * 4;
  unsigned short* op = obuf + h * 64;
#pragma unroll
  for (int dt = 0; dt < 4; ++dt)
#pragma unroll
    for (int r = 0; r < 4; ++r) {
      float v = o_acc[dt][r] * rl[r];
      op[(size_t)(orow + r) * DD + dt * 16 + l15] = f2bf(v);
    }
}

// ---------------- launch: batched across B with ws_size-adaptive chunking ----------------
extern "C" void kernel_launch(void* const* d_in, const int* in_sizes, int n_in,
                              void* d_out, int out_size, void* d_ws, size_t ws_size,
                              hipStream_t stream) {
  const float* x    = (const float*)d_in[0];
  const float* wr   = (const float*)d_in[1];
  const float* ln1s = (const float*)d_in[2];
  const float* ln1b = (const float*)d_in[3];
  const float* ln2s = (const float*)d_in[4];
  const float* ln2b = (const float*)d_in[5];
  const float* wqkv = (const float*)d_in[6];
  const float* wout = (const float*)d_in[7];
  const float* w1   = (const float*)d_in[8];
  const float* w2   = (const float*)d_in[9];
  const float* w3   = (const float*)d_in[10];
  float* out = (float*)d_out;
  char* ws = (char*)d_ws;

  // control region [0, 1 MiB)
  double* dots  = (double*)(ws + 0);        // 128 KiB
  float*  sig   = (float*)(ws + 131072);    // 64 KiB
  int*    flags = (int*)(ws + 196608);      // 64 KiB
  int*    idx   = (int*)(ws + 262144);      // 32 KiB (global token indices)
  float*  means = (float*)(ws + 294912);    // 16 B
  // bf16 weight copies [1 MiB, 33 MiB)
  unsigned short* wqkv_h = (unsigned short*)(ws + ((size_t)1 << 20));   // 6 MiB
  unsigned short* wout_h = (unsigned short*)(ws + ((size_t)7 << 20));   // 2 MiB
  unsigned short* w1_h   = (unsigned short*)(ws + ((size_t)9 << 20));   // 8 MiB
  unsigned short* w2_h   = (unsigned short*)(ws + ((size_t)17 << 20));  // 8 MiB
  unsigned short* w3_h   = (unsigned short*)(ws + ((size_t)25 << 20));  // 8 MiB
  const size_t base = (size_t)33 << 20;

  // out = x (pass-through for unselected tokens), f32, 64 MiB
  hipMemcpyAsync(out, x, (size_t)BB * TT * DD * sizeof(float),
                 hipMemcpyDeviceToDevice, stream);

  // weight conversions f32 -> bf16
  cvt_kernel<<<dim3(3 * DD * DD / 1024), dim3(256), 0, stream>>>(wqkv, wqkv_h, 3 * DD * DD);
  cvt_kernel<<<dim3(DD * DD / 1024), dim3(256), 0, stream>>>(wout, wout_h, DD * DD);
  cvt_kernel<<<dim3(DFF * DD / 1024), dim3(256), 0, stream>>>(w1, w1_h, DFF * DD);
  cvt_kernel<<<dim3(DFF * DD / 1024), dim3(256), 0, stream>>>(w2, w2_h, DFF * DD);
  cvt_kernel<<<dim3(DD * DFF / 1024), dim3(256), 0, stream>>>(w3, w3_h, DD * DFF);

  router_kernel<<<dim3(BB * TT / 4), dim3(256), 0, stream>>>(x, wr, dots, sig);
  rank_kernel<<<dim3(BB * 16), dim3(256), 0, stream>>>(dots, flags);
  compact_kernel<<<dim3(BB), dim3(256), 0, stream>>>(flags, sig, idx, means);
  aux_kernel<<<dim3(1), dim3(64), 0, stream>>>(means, out + (size_t)BB * TT * DD);

  // per-row buffer bytes: x1 4096 + norm 2048 + max(qkv 6144 + obuf 2048, gbuf 8192) = 14336
  int cb = 4;  // batches per chunk
  while (cb > 1 && base + (size_t)cb * KSEL * 14336 > ws_size) cb >>= 1;

  for (int c0 = 0; c0 < BB; c0 += cb) {
    const int R = cb * KSEL;  // rows in this chunk
    const int* gidx = idx + (size_t)c0 * KSEL;
    float*          x1    = (float*)(ws + base);
    unsigned short* normb = (unsigned short*)(ws + base + (size_t)R * 4096);
    unsigned short* qkvb  = (unsigned short*)(ws + base + (size_t)R * 6144);
    unsigned short* obufb = (unsigned short*)(ws + base + (size_t)R * 12288);
    unsigned short* gbuf  = qkvb;  // overlays dead qkv+obuf (R*8192 <= R*6144 + R*2048)

    // ln1 on gathered selected tokens -> bf16
    ln_kernel<<<dim3(R), dim3(256), 0, stream>>>(x, gidx, ln1s, ln1b, normb);

    // qkv = normed @ w_qkv^T  (R x 3072, K=1024) -> bf16
    gemm_bt<0><<<dim3(R / 128, 3 * DD / 128), dim3(256), 0, stream>>>(
        normb, wqkv_h, DD, 3 * DD, qkvb, nullptr, nullptr, nullptr);

    // attention -> bf16 obuf (per-batch via blockIdx.z)
    attn_kernel<<<dim3(KSEL / 64, HH, cb), dim3(256), 0, stream>>>(qkvb, obufb);

    // x1 = x_sel + o @ w_out^T  -> f32
    gemm_bt<1><<<dim3(R / 128, DD / 128), dim3(256), 0, stream>>>(
        obufb, wout_h, DD, DD, nullptr, gidx, x, x1);

    // ln2 -> bf16
    ln_kernel<<<dim3(R), dim3(256), 0, stream>>>(x1, nullptr, ln2s, ln2b, normb);

    // g = silu(h@w1^T) * (h@w2^T)  (R x 4096, K=1024) -> bf16
    gemm_dual<<<dim3(R / 128, DFF / 128), dim3(256), 0, stream>>>(
        normb, w1_h, w2_h, gbuf, DD, DFF);

    // out[gidx, :] = x1 + g @ w3^T  (K=4096) -> f32 scatter
    gemm_bt<2><<<dim3(R / 128, DD / 128), dim3(256), 0, stream>>>(
        gbuf, w3_h, DFF, DD, nullptr, gidx, x1, out);
  }
}

// Round 4
// 812.284 us; speedup vs baseline: 1.9400x; 1.1661x over previous
//
#include <hip/hip_runtime.h>
#include <hip/hip_bf16.h>
#include <math.h>

#define BB 4
#define TT 4096
#define DD 1024
#define HH 16
#define DFF 4096
#define KSEL 2048

typedef __attribute__((ext_vector_type(8))) short short8;
typedef __attribute__((ext_vector_type(4))) float f32x4;

__device__ __forceinline__ unsigned short f2bf(float f) {
  union { float f; unsigned int i; } v; v.f = f;
  unsigned int x = v.i;
  unsigned int r = (x + 0x7fffu + ((x >> 16) & 1u)) >> 16;
  return (unsigned short)r;
}
__device__ __forceinline__ float bf2f(unsigned short u) {
  union { unsigned int i; float f; } v; v.i = ((unsigned int)u) << 16; return v.f;
}

// native 2^x (v_exp_f32) — avoids glibc __exp2f macro collision
__device__ __forceinline__ float exp2g(float x) { return __builtin_amdgcn_exp2f(x); }

// async global->LDS, 16B per lane; lds ptr must be wave-uniform (lane0 = wave base)
__device__ __forceinline__ void gload16(const void* g, void* l) {
  __builtin_amdgcn_global_load_lds(
      (const __attribute__((address_space(1))) void*)g,
      (__attribute__((address_space(3))) void*)l,
      16, 0, 0);
}

// ---------------- f32 -> bf16 conversion (weights) ----------------
__global__ void cvt_kernel(const float* __restrict__ src, unsigned short* __restrict__ dst, int n) {
  int i = (blockIdx.x * 256 + threadIdx.x) * 4;
  if (i + 3 < n) {
    float4 v = *(const float4*)(src + i);
    ushort4 o;
    o.x = f2bf(v.x); o.y = f2bf(v.y); o.z = f2bf(v.z); o.w = f2bf(v.w);
    *(ushort4*)(dst + i) = o;
  }
}

// ---------------- router: f64 dot per token + sigmoid ----------------
__global__ void router_kernel(const float* __restrict__ x,
                              const float* __restrict__ wr,
                              double* __restrict__ dots, float* __restrict__ sig) {
  int token = blockIdx.x * 4 + (threadIdx.x >> 6);
  int lane = threadIdx.x & 63;
  const float* xr = x + (size_t)token * DD;
  double s = 0.0;
  for (int j = lane; j < DD; j += 64)
    s += (double)xr[j] * (double)wr[j];
  for (int o = 32; o > 0; o >>= 1) s += __shfl_down(s, o);
  if (lane == 0) {
    dots[token] = s;
    sig[token] = 1.0f / (1.0f + expf((float)(-s)));
  }
}

// ---------------- rank: count tokens strictly ahead; flag top-k ----------------
__global__ void rank_kernel(const double* __restrict__ dots, int* __restrict__ flags) {
  __shared__ double sd[TT];
  int b = blockIdx.x >> 4;
  int chunk = blockIdx.x & 15;
  const double* drow = dots + (size_t)b * TT;
  for (int j = threadIdx.x; j < TT; j += 256) sd[j] = drow[j];
  __syncthreads();
  int i = chunk * 256 + threadIdx.x;
  double di = sd[i];
  int cnt = 0;
  for (int j = 0; j < TT; ++j) {
    double dj = sd[j];
    cnt += (int)((dj > di) || (dj == di && j < i));
  }
  flags[(size_t)b * TT + i] = (cnt < KSEL) ? 1 : 0;
}

// ---------------- compact: ascending selected GLOBAL indices (b*TT+t) + batch mean ----------------
__global__ void compact_kernel(const int* __restrict__ flags, const float* __restrict__ sig,
                               int* __restrict__ idx, float* __restrict__ means) {
  __shared__ int part[256];
  __shared__ float ssum[256];
  int b = blockIdx.x;
  const int* f = flags + (size_t)b * TT;
  int tid = threadIdx.x;
  int local = 0; float fs = 0.f;
  for (int j = 0; j < 16; ++j) {
    local += f[tid * 16 + j];
    fs += sig[(size_t)b * TT + tid * 16 + j];
  }
  part[tid] = local; ssum[tid] = fs;
  __syncthreads();
  if (tid == 0) {
    int run = 0;
    for (int t = 0; t < 256; ++t) { int c = part[t]; part[t] = run; run += c; }
    float tot = 0.f;
    for (int t = 0; t < 256; ++t) tot += ssum[t];
    means[b] = tot / (float)TT;
  }
  __syncthreads();
  int pos = part[tid];
  for (int j = 0; j < 16; ++j) {
    int t = tid * 16 + j;
    if (f[t]) { idx[(size_t)b * KSEL + pos] = b * TT + t; ++pos; }
  }
}

__global__ void aux_kernel(const float* __restrict__ means, float* __restrict__ out_aux) {
  if (threadIdx.x == 0 && blockIdx.x == 0) {
    float m = 0.f;
    for (int b = 0; b < BB; ++b) m += means[b];
    m *= (1.0f / BB);
    float v = 0.f;
    for (int b = 0; b < BB; ++b) { float d = means[b] - m; v += d * d; }
    v /= (float)(BB - 1);
    *out_aux = v;
  }
}

// ---------------- layernorm: f32 src (optional gather via GLOBAL idx), bf16 dst ----------------
__global__ void ln_kernel(const float* __restrict__ src,
                          const int* __restrict__ idx,
                          const float* __restrict__ scale,
                          const float* __restrict__ bias,
                          unsigned short* __restrict__ dst) {
  int r = blockIdx.x;
  const float* row;
  if (idx) {
    int t = idx[r];                 // global token index b*TT + t
    row = src + (size_t)t * DD;
  } else {
    row = src + (size_t)r * DD;
  }
  __shared__ float red[8];
  __shared__ float mv[2];
  int tid = threadIdx.x;
  float vals[4];
  float s = 0.f, ss = 0.f;
  for (int j = 0; j < 4; ++j) {
    float v = row[tid + 256 * j];
    vals[j] = v; s += v; ss += v * v;
  }
  for (int o = 32; o > 0; o >>= 1) { s += __shfl_down(s, o); ss += __shfl_down(ss, o); }
  int wid = tid >> 6, lane = tid & 63;
  if (lane == 0) { red[wid] = s; red[wid + 4] = ss; }
  __syncthreads();
  if (tid == 0) {
    float a = red[0] + red[1] + red[2] + red[3];
    float q = red[4] + red[5] + red[6] + red[7];
    float mean = a / (float)DD;
    float var = fmaxf(q / (float)DD - mean * mean, 0.f);
    mv[0] = mean; mv[1] = rsqrtf(var + 1e-5f);
  }
  __syncthreads();
  float mean = mv[0], rst = mv[1];
  unsigned short* drow = dst + (size_t)r * DD;
  for (int j = 0; j < 4; ++j) {
    int c = tid + 256 * j;
    float v = (vals[j] - mean) * rst * scale[c] + bias[c];
    drow[c] = f2bf(v);
  }
}

// ---------------- BT-form MFMA GEMM (m97 structure): acc = A[M,K] * W[N,K]^T ----------------
// linear LDS [128][32] + global_load_lds width 16, 2 barriers per K-step.
// EPI 0: Cb[row*N+col] = bf16(acc)                          (qkv)
// EPI 1: fout[row*DD+col] = xin[gidx[row]*DD+col] + acc     (x1 = x_sel + attn, f32)
// EPI 2: fout[gidx[row]*DD+col] = xin[row*DD+col] + acc     (scatter out = x1 + ffn, f32)
template <int EPI>
__launch_bounds__(256, 2)
__global__ void gemm_bt(const unsigned short* __restrict__ A,
                        const unsigned short* __restrict__ W,
                        int K, int N,
                        unsigned short* __restrict__ Cb,
                        const int* __restrict__ idx,
                        const float* __restrict__ xin,
                        float* __restrict__ fout) {
  __shared__ unsigned short As[128 * 32];
  __shared__ unsigned short Bs[128 * 32];
  int bm = blockIdx.x, bn = blockIdx.y;
  int tid = threadIdx.x;
  int wid = tid >> 6, lane = tid & 63;
  int quad = lane >> 4, l15 = lane & 15;
  int wm = (wid >> 1) * 64, wn = (wid & 1) * 64;

  f32x4 acc[4][4] = {};
  const int arow0 = bm * 128, brow0 = bn * 128;
  int srow = tid >> 2;
  int scol = (tid & 3) * 8;
  const unsigned short* Ag = A + (size_t)(arow0 + srow) * K + scol;
  const unsigned short* Wg = W + (size_t)(brow0 + srow) * K + scol;
  // wave-uniform LDS staging base: wave w covers rows 16w..16w+15 (1024B)
  unsigned short* AsW = As + (size_t)(tid & 192) * 8;
  unsigned short* BsW = Bs + (size_t)(tid & 192) * 8;

  for (int k0 = 0; k0 < K; k0 += 32) {
    __syncthreads();  // prior reads drained before overwrite
    gload16(Ag + k0, AsW);
    gload16(Ag + (size_t)64 * K + k0, AsW + 2048);
    gload16(Wg + k0, BsW);
    gload16(Wg + (size_t)64 * K + k0, BsW + 2048);
    __syncthreads();  // vmcnt(0) drain -> staged data visible
    short8 af[4], bfr[4];
    for (int t = 0; t < 4; ++t) af[t]  = *(const short8*)&As[(wm + t * 16 + l15) * 32 + quad * 8];
    for (int t = 0; t < 4; ++t) bfr[t] = *(const short8*)&Bs[(wn + t * 16 + l15) * 32 + quad * 8];
    for (int i = 0; i < 4; ++i)
      for (int j = 0; j < 4; ++j)
        acc[i][j] = __builtin_amdgcn_mfma_f32_16x16x32_bf16(af[i], bfr[j], acc[i][j], 0, 0, 0);
  }

  for (int i = 0; i < 4; ++i)
    for (int j = 0; j < 4; ++j)
      for (int r = 0; r < 4; ++r) {
        int row = arow0 + wm + i * 16 + quad * 4 + r;
        int col = brow0 + wn + j * 16 + l15;
        float v = acc[i][j][r];
        if (EPI == 0) {
          Cb[(size_t)row * N + col] = f2bf(v);
        } else if (EPI == 1) {
          int t = idx[row];
          fout[(size_t)row * DD + col] = xin[(size_t)t * DD + col] + v;
        } else {
          int t = idx[row];
          fout[(size_t)t * DD + col] = xin[(size_t)row * DD + col] + v;
        }
      }
}

// ---------------- dual-B GEMM for SwiGLU (m97 structure): g = silu(A*W1^T) * (A*W2^T) ----------------
__launch_bounds__(256, 2)
__global__ void gemm_dual(const unsigned short* __restrict__ A,
                          const unsigned short* __restrict__ W1,
                          const unsigned short* __restrict__ W2,
                          unsigned short* __restrict__ G,
                          int K, int N) {
  __shared__ unsigned short As[128 * 32];
  __shared__ unsigned short B1s[128 * 32];
  __shared__ unsigned short B2s[128 * 32];
  int bm = blockIdx.x, bn = blockIdx.y;
  int tid = threadIdx.x;
  int wid = tid >> 6, lane = tid & 63;
  int quad = lane >> 4, l15 = lane & 15;
  int wm = (wid >> 1) * 64, wn = (wid & 1) * 64;

  f32x4 acc1[4][4] = {};
  f32x4 acc2[4][4] = {};
  const int arow0 = bm * 128, brow0 = bn * 128;
  int srow = tid >> 2;
  int scol = (tid & 3) * 8;
  const unsigned short* Ag  = A  + (size_t)(arow0 + srow) * K + scol;
  const unsigned short* W1g = W1 + (size_t)(brow0 + srow) * K + scol;
  const unsigned short* W2g = W2 + (size_t)(brow0 + srow) * K + scol;
  unsigned short* AsW  = As  + (size_t)(tid & 192) * 8;
  unsigned short* B1sW = B1s + (size_t)(tid & 192) * 8;
  unsigned short* B2sW = B2s + (size_t)(tid & 192) * 8;

  for (int k0 = 0; k0 < K; k0 += 32) {
    __syncthreads();
    gload16(Ag + k0, AsW);
    gload16(Ag + (size_t)64 * K + k0, AsW + 2048);
    gload16(W1g + k0, B1sW);
    gload16(W1g + (size_t)64 * K + k0, B1sW + 2048);
    gload16(W2g + k0, B2sW);
    gload16(W2g + (size_t)64 * K + k0, B2sW + 2048);
    __syncthreads();
    short8 af[4], b1f[4], b2f[4];
    for (int t = 0; t < 4; ++t) af[t]  = *(const short8*)&As[(wm + t * 16 + l15) * 32 + quad * 8];
    for (int t = 0; t < 4; ++t) b1f[t] = *(const short8*)&B1s[(wn + t * 16 + l15) * 32 + quad * 8];
    for (int t = 0; t < 4; ++t) b2f[t] = *(const short8*)&B2s[(wn + t * 16 + l15) * 32 + quad * 8];
    for (int i = 0; i < 4; ++i)
      for (int j = 0; j < 4; ++j) {
        acc1[i][j] = __builtin_amdgcn_mfma_f32_16x16x32_bf16(af[i], b1f[j], acc1[i][j], 0, 0, 0);
        acc2[i][j] = __builtin_amdgcn_mfma_f32_16x16x32_bf16(af[i], b2f[j], acc2[i][j], 0, 0, 0);
      }
  }

  for (int i = 0; i < 4; ++i)
    for (int j = 0; j < 4; ++j)
      for (int r = 0; r < 4; ++r) {
        int row = arow0 + wm + i * 16 + quad * 4 + r;
        int col = brow0 + wn + j * 16 + l15;
        float u1 = acc1[i][j][r];
        float u2 = acc2[i][j][r];
        float sg = u1 / (1.0f + __expf(-u1));  // silu (native exp)
        G[(size_t)row * N + col] = f2bf(sg * u2);
      }
}

// ---------------- flash attention: QBLK=128, 8 waves, swapped-QK^T in-register softmax ----------------
// S^T = mfma(K_frag, Q_frag): each lane holds one q-row's 16 scores per 64-key tile.
// exp2-domain online softmax with defer-max; packed cvt_pk P->LDS (per-warp, no barrier).
__launch_bounds__(512, 4)
__global__ void attn_kernel(const unsigned short* __restrict__ qkv_all,
                            unsigned short* __restrict__ obuf_all) {
  int qb = blockIdx.x;   // 0..15 (128 q-rows each)
  int h = blockIdx.y;    // 0..15
  const unsigned short* qkv = qkv_all + (size_t)blockIdx.z * KSEL * 3 * DD;
  unsigned short* obuf = obuf_all + (size_t)blockIdx.z * KSEL * DD;
  int tid = threadIdx.x, wid = tid >> 6, lane = tid & 63;
  int quad = lane >> 4, l15 = lane & 15;

  __shared__ unsigned short Ks[64][68];     // keys x dims
  __shared__ unsigned short Vt[64][68];     // V^T: dims x keys
  __shared__ unsigned short Ps[8][16][72];  // per-warp P: q-rows x keys (16B-aligned rows)

  const float SCL = 0.125f * 1.44269504f;   // scale * log2(e): exp2-domain softmax

  int qrow = qb * 128 + wid * 16 + l15;
  const unsigned short* qptr = qkv + (size_t)qrow * (3 * DD) + h * 64;
  short8 aq0 = *(const short8*)(qptr + quad * 8);
  short8 aq1 = *(const short8*)(qptr + 32 + quad * 8);

  float m_run = -1e30f, l_run = 0.f;        // per lane: q-row = l15 (raw-score domain)
  f32x4 o_acc[4] = {};

  int skey = tid >> 3;          // 0..63
  int scol = (tid & 7) * 8;     // 0..56
  const unsigned short* kbase = qkv + DD + h * 64;
  const unsigned short* vbase = qkv + 2 * DD + h * 64;

  for (int kt = 0; kt < KSEL / 64; ++kt) {
    int key0 = kt * 64;
    uint4 kv = *(const uint4*)(kbase + (size_t)(key0 + skey) * (3 * DD) + scol);
    uint4 vv = *(const uint4*)(vbase + (size_t)(key0 + skey) * (3 * DD) + scol);
    __syncthreads();
    *(uint4*)&Ks[skey][scol] = kv;
    {
      const unsigned short* vp = (const unsigned short*)&vv;
#pragma unroll
      for (int j = 0; j < 8; ++j) Vt[scol + j][skey] = vp[j];
    }
    __syncthreads();

    // S^T: st[t][r] = score(key = 16t + 4*quad + r, q = l15)   (raw, unscaled)
    f32x4 st[4];
#pragma unroll
    for (int t = 0; t < 4; ++t) {
      f32x4 z = {0.f, 0.f, 0.f, 0.f};
      short8 ka = *(const short8*)&Ks[t * 16 + l15][quad * 8];
      short8 kb = *(const short8*)&Ks[t * 16 + l15][32 + quad * 8];
      z = __builtin_amdgcn_mfma_f32_16x16x32_bf16(ka, aq0, z, 0, 0, 0);
      z = __builtin_amdgcn_mfma_f32_16x16x32_bf16(kb, aq1, z, 0, 0, 0);
      st[t] = z;
    }

    // row max: 15 in-register + cross-quad (same l15 -> same q)
    float mx = fmaxf(fmaxf(st[0][0], st[0][1]), fmaxf(st[0][2], st[0][3]));
#pragma unroll
    for (int t = 1; t < 4; ++t)
      mx = fmaxf(mx, fmaxf(fmaxf(st[t][0], st[t][1]), fmaxf(st[t][2], st[t][3])));
    mx = fmaxf(mx, __shfl_xor(mx, 16));
    mx = fmaxf(mx, __shfl_xor(mx, 32));

    // defer-max: only rescale when max grew by > 64 raw (2^11.5 headroom in p)
    if (!__all(mx <= m_run + 64.0f)) {
      float mnew = fmaxf(m_run, mx);
      float alpha = exp2g((m_run - mnew) * SCL);
      float a0 = __shfl(alpha, quad * 4 + 0);
      float a1 = __shfl(alpha, quad * 4 + 1);
      float a2 = __shfl(alpha, quad * 4 + 2);
      float a3 = __shfl(alpha, quad * 4 + 3);
#pragma unroll
      for (int dt = 0; dt < 4; ++dt) {
        o_acc[dt][0] *= a0; o_acc[dt][1] *= a1;
        o_acc[dt][2] *= a2; o_acc[dt][3] *= a3;
      }
      l_run *= alpha;
      m_run = mnew;
    }

    float msc = m_run * SCL;
    float p[4][4];
    float ls = 0.f;
#pragma unroll
    for (int t = 0; t < 4; ++t)
#pragma unroll
      for (int r = 0; r < 4; ++r) {
        float e = exp2g(__builtin_fmaf(st[t][r], SCL, -msc));
        p[t][r] = e;
        ls += e;
      }
    ls += __shfl_xor(ls, 16);
    ls += __shfl_xor(ls, 32);
    l_run += ls;

    // P -> per-warp LDS (packed pairs; wave-local, no barrier needed)
#pragma unroll
    for (int t = 0; t < 4; ++t)
#pragma unroll
      for (int hh = 0; hh < 2; ++hh) {
        unsigned int w;
        asm("v_cvt_pk_bf16_f32 %0, %1, %2" : "=v"(w) : "v"(p[t][2 * hh]), "v"(p[t][2 * hh + 1]));
        *(unsigned int*)&Ps[wid][l15][t * 16 + quad * 4 + 2 * hh] = w;
      }

    short8 ap0 = *(const short8*)&Ps[wid][l15][quad * 8];
    short8 ap1 = *(const short8*)&Ps[wid][l15][32 + quad * 8];
#pragma unroll
    for (int dt = 0; dt < 4; ++dt) {
      short8 vf0 = *(const short8*)&Vt[dt * 16 + l15][quad * 8];
      short8 vf1 = *(const short8*)&Vt[dt * 16 + l15][32 + quad * 8];
      o_acc[dt] = __builtin_amdgcn_mfma_f32_16x16x32_bf16(ap0, vf0, o_acc[dt], 0, 0, 0);
      o_acc[dt] = __builtin_amdgcn_mfma_f32_16x16x32_bf16(ap1, vf1, o_acc[dt], 0, 0, 0);
    }
  }

  // epilogue: l for o_acc's rows (q = quad*4 + r) via shfl
  float rl[4];
#pragma unroll
  for (int r = 0; r < 4; ++r) rl[r] = 1.0f / __shfl(l_run, quad * 4 + r);
  int orow = qb * 128 + wid * 16 + quad * 4;
  unsigned short* op = obuf + h * 64;
#pragma unroll
  for (int dt = 0; dt < 4; ++dt)
#pragma unroll
    for (int r = 0; r < 4; ++r) {
      float v = o_acc[dt][r] * rl[r];
      op[(size_t)(orow + r) * DD + dt * 16 + l15] = f2bf(v);
    }
}

// ---------------- launch: batched across B with ws_size-adaptive chunking ----------------
extern "C" void kernel_launch(void* const* d_in, const int* in_sizes, int n_in,
                              void* d_out, int out_size, void* d_ws, size_t ws_size,
                              hipStream_t stream) {
  const float* x    = (const float*)d_in[0];
  const float* wr   = (const float*)d_in[1];
  const float* ln1s = (const float*)d_in[2];
  const float* ln1b = (const float*)d_in[3];
  const float* ln2s = (const float*)d_in[4];
  const float* ln2b = (const float*)d_in[5];
  const float* wqkv = (const float*)d_in[6];
  const float* wout = (const float*)d_in[7];
  const float* w1   = (const float*)d_in[8];
  const float* w2   = (const float*)d_in[9];
  const float* w3   = (const float*)d_in[10];
  float* out = (float*)d_out;
  char* ws = (char*)d_ws;

  // control region [0, 1 MiB)
  double* dots  = (double*)(ws + 0);        // 128 KiB
  float*  sig   = (float*)(ws + 131072);    // 64 KiB
  int*    flags = (int*)(ws + 196608);      // 64 KiB
  int*    idx   = (int*)(ws + 262144);      // 32 KiB (global token indices)
  float*  means = (float*)(ws + 294912);    // 16 B
  // bf16 weight copies [1 MiB, 33 MiB)
  unsigned short* wqkv_h = (unsigned short*)(ws + ((size_t)1 << 20));   // 6 MiB
  unsigned short* wout_h = (unsigned short*)(ws + ((size_t)7 << 20));   // 2 MiB
  unsigned short* w1_h   = (unsigned short*)(ws + ((size_t)9 << 20));   // 8 MiB
  unsigned short* w2_h   = (unsigned short*)(ws + ((size_t)17 << 20));  // 8 MiB
  unsigned short* w3_h   = (unsigned short*)(ws + ((size_t)25 << 20));  // 8 MiB
  const size_t base = (size_t)33 << 20;

  // out = x (pass-through for unselected tokens), f32, 64 MiB
  hipMemcpyAsync(out, x, (size_t)BB * TT * DD * sizeof(float),
                 hipMemcpyDeviceToDevice, stream);

  // weight conversions f32 -> bf16
  cvt_kernel<<<dim3(3 * DD * DD / 1024), dim3(256), 0, stream>>>(wqkv, wqkv_h, 3 * DD * DD);
  cvt_kernel<<<dim3(DD * DD / 1024), dim3(256), 0, stream>>>(wout, wout_h, DD * DD);
  cvt_kernel<<<dim3(DFF * DD / 1024), dim3(256), 0, stream>>>(w1, w1_h, DFF * DD);
  cvt_kernel<<<dim3(DFF * DD / 1024), dim3(256), 0, stream>>>(w2, w2_h, DFF * DD);
  cvt_kernel<<<dim3(DD * DFF / 1024), dim3(256), 0, stream>>>(w3, w3_h, DD * DFF);

  router_kernel<<<dim3(BB * TT / 4), dim3(256), 0, stream>>>(x, wr, dots, sig);
  rank_kernel<<<dim3(BB * 16), dim3(256), 0, stream>>>(dots, flags);
  compact_kernel<<<dim3(BB), dim3(256), 0, stream>>>(flags, sig, idx, means);
  aux_kernel<<<dim3(1), dim3(64), 0, stream>>>(means, out + (size_t)BB * TT * DD);

  // per-row buffer bytes: x1 4096 + norm 2048 + max(qkv 6144 + obuf 2048, gbuf 8192) = 14336
  int cb = 4;  // batches per chunk
  while (cb > 1 && base + (size_t)cb * KSEL * 14336 > ws_size) cb >>= 1;

  for (int c0 = 0; c0 < BB; c0 += cb) {
    const int R = cb * KSEL;  // rows in this chunk
    const int* gidx = idx + (size_t)c0 * KSEL;
    float*          x1    = (float*)(ws + base);
    unsigned short* normb = (unsigned short*)(ws + base + (size_t)R * 4096);
    unsigned short* qkvb  = (unsigned short*)(ws + base + (size_t)R * 6144);
    unsigned short* obufb = (unsigned short*)(ws + base + (size_t)R * 12288);
    unsigned short* gbuf  = qkvb;  // overlays dead qkv+obuf (R*8192 <= R*6144 + R*2048)

    // ln1 on gathered selected tokens -> bf16
    ln_kernel<<<dim3(R), dim3(256), 0, stream>>>(x, gidx, ln1s, ln1b, normb);

    // qkv = normed @ w_qkv^T  (R x 3072, K=1024) -> bf16
    gemm_bt<0><<<dim3(R / 128, 3 * DD / 128), dim3(256), 0, stream>>>(
        normb, wqkv_h, DD, 3 * DD, qkvb, nullptr, nullptr, nullptr);

    // attention -> bf16 obuf (per-batch via blockIdx.z)
    attn_kernel<<<dim3(KSEL / 128, HH, cb), dim3(512), 0, stream>>>(qkvb, obufb);

    // x1 = x_sel + o @ w_out^T  -> f32
    gemm_bt<1><<<dim3(R / 128, DD / 128), dim3(256), 0, stream>>>(
        obufb, wout_h, DD, DD, nullptr, gidx, x, x1);

    // ln2 -> bf16
    ln_kernel<<<dim3(R), dim3(256), 0, stream>>>(x1, nullptr, ln2s, ln2b, normb);

    // g = silu(h@w1^T) * (h@w2^T)  (R x 4096, K=1024) -> bf16
    gemm_dual<<<dim3(R / 128, DFF / 128), dim3(256), 0, stream>>>(
        normb, w1_h, w2_h, gbuf, DD, DFF);

    // out[gidx, :] = x1 + g @ w3^T  (K=4096) -> f32 scatter
    gemm_bt<2><<<dim3(R / 128, DD / 128), dim3(256), 0, stream>>>(
        gbuf, w3_h, DFF, DD, nullptr, gidx, x1, out);
  }
}

// Round 5
// 804.110 us; speedup vs baseline: 1.9597x; 1.0102x over previous
//
#include <hip/hip_runtime.h>
#include <hip/hip_bf16.h>
#include <math.h>

#define BB 4
#define TT 4096
#define DD 1024
#define HH 16
#define DFF 4096
#define KSEL 2048

typedef __attribute__((ext_vector_type(8))) short short8;
typedef __attribute__((ext_vector_type(4))) float f32x4;

__device__ __forceinline__ unsigned short f2bf(float f) {
  union { float f; unsigned int i; } v; v.f = f;
  unsigned int x = v.i;
  unsigned int r = (x + 0x7fffu + ((x >> 16) & 1u)) >> 16;
  return (unsigned short)r;
}
__device__ __forceinline__ float bf2f(unsigned short u) {
  union { unsigned int i; float f; } v; v.i = ((unsigned int)u) << 16; return v.f;
}

// native 2^x (v_exp_f32) — avoids glibc __exp2f macro collision
__device__ __forceinline__ float exp2g(float x) { return __builtin_amdgcn_exp2f(x); }

// async global->LDS, 16B per lane; lds ptr must be wave-uniform (lane0 = wave base)
__device__ __forceinline__ void gload16(const void* g, void* l) {
  __builtin_amdgcn_global_load_lds(
      (const __attribute__((address_space(1))) void*)g,
      (__attribute__((address_space(3))) void*)l,
      16, 0, 0);
}

// ---------------- merged f32 -> bf16 conversion for all 5 weight tensors ----------------
__global__ void cvt_all_kernel(const float* __restrict__ s0, const float* __restrict__ s1,
                               const float* __restrict__ s2, const float* __restrict__ s3,
                               const float* __restrict__ s4,
                               unsigned short* __restrict__ d0, unsigned short* __restrict__ d1,
                               unsigned short* __restrict__ d2, unsigned short* __restrict__ d3,
                               unsigned short* __restrict__ d4) {
  const long n0 = (long)3 * DD * DD;     // wqkv  3M
  const long n1 = (long)DD * DD;         // wout  1M
  const long n2 = (long)DFF * DD;        // w1/w2/w3  4M each
  long i = ((long)blockIdx.x * 256 + threadIdx.x) * 4;
  const float* src; unsigned short* dst; long off;
  if (i < n0)                    { src = s0; dst = d0; off = i; }
  else if (i < n0 + n1)          { src = s1; dst = d1; off = i - n0; }
  else if (i < n0 + n1 + n2)     { src = s2; dst = d2; off = i - n0 - n1; }
  else if (i < n0 + n1 + 2*n2)   { src = s3; dst = d3; off = i - n0 - n1 - n2; }
  else                           { src = s4; dst = d4; off = i - n0 - n1 - 2*n2; }
  float4 v = *(const float4*)(src + off);
  ushort4 o;
  o.x = f2bf(v.x); o.y = f2bf(v.y); o.z = f2bf(v.z); o.w = f2bf(v.w);
  *(ushort4*)(dst + off) = o;
}

// ---------------- router: f64 dot per token + sigmoid ----------------
__global__ void router_kernel(const float* __restrict__ x,
                              const float* __restrict__ wr,
                              double* __restrict__ dots, float* __restrict__ sig) {
  int token = blockIdx.x * 4 + (threadIdx.x >> 6);
  int lane = threadIdx.x & 63;
  const float* xr = x + (size_t)token * DD;
  double s = 0.0;
  for (int j = lane; j < DD; j += 64)
    s += (double)xr[j] * (double)wr[j];
  for (int o = 32; o > 0; o >>= 1) s += __shfl_down(s, o);
  if (lane == 0) {
    dots[token] = s;
    sig[token] = 1.0f / (1.0f + expf((float)(-s)));
  }
}

// ---------------- rank: count tokens strictly ahead; flag top-k ----------------
__global__ void rank_kernel(const double* __restrict__ dots, int* __restrict__ flags) {
  __shared__ double sd[TT];
  int b = blockIdx.x >> 4;
  int chunk = blockIdx.x & 15;
  const double* drow = dots + (size_t)b * TT;
  for (int j = threadIdx.x; j < TT; j += 256) sd[j] = drow[j];
  __syncthreads();
  int i = chunk * 256 + threadIdx.x;
  double di = sd[i];
  int cnt = 0;
  for (int j = 0; j < TT; ++j) {
    double dj = sd[j];
    cnt += (int)((dj > di) || (dj == di && j < i));
  }
  flags[(size_t)b * TT + i] = (cnt < KSEL) ? 1 : 0;
}

// ---------------- compact: ascending selected GLOBAL indices (b*TT+t) + batch mean ----------------
__global__ void compact_kernel(const int* __restrict__ flags, const float* __restrict__ sig,
                               int* __restrict__ idx, float* __restrict__ means) {
  __shared__ int part[256];
  __shared__ float ssum[256];
  int b = blockIdx.x;
  const int* f = flags + (size_t)b * TT;
  int tid = threadIdx.x;
  int local = 0; float fs = 0.f;
  for (int j = 0; j < 16; ++j) {
    local += f[tid * 16 + j];
    fs += sig[(size_t)b * TT + tid * 16 + j];
  }
  part[tid] = local; ssum[tid] = fs;
  __syncthreads();
  if (tid == 0) {
    int run = 0;
    for (int t = 0; t < 256; ++t) { int c = part[t]; part[t] = run; run += c; }
    float tot = 0.f;
    for (int t = 0; t < 256; ++t) tot += ssum[t];
    means[b] = tot / (float)TT;
  }
  __syncthreads();
  int pos = part[tid];
  for (int j = 0; j < 16; ++j) {
    int t = tid * 16 + j;
    if (f[t]) { idx[(size_t)b * KSEL + pos] = b * TT + t; ++pos; }
  }
}

__global__ void aux_kernel(const float* __restrict__ means, float* __restrict__ out_aux) {
  if (threadIdx.x == 0 && blockIdx.x == 0) {
    float m = 0.f;
    for (int b = 0; b < BB; ++b) m += means[b];
    m *= (1.0f / BB);
    float v = 0.f;
    for (int b = 0; b < BB; ++b) { float d = means[b] - m; v += d * d; }
    v /= (float)(BB - 1);
    *out_aux = v;
  }
}

// ---------------- layernorm: f32 src (optional gather via GLOBAL idx), bf16 dst ----------------
__global__ void ln_kernel(const float* __restrict__ src,
                          const int* __restrict__ idx,
                          const float* __restrict__ scale,
                          const float* __restrict__ bias,
                          unsigned short* __restrict__ dst) {
  int r = blockIdx.x;
  const float* row;
  if (idx) {
    int t = idx[r];                 // global token index b*TT + t
    row = src + (size_t)t * DD;
  } else {
    row = src + (size_t)r * DD;
  }
  __shared__ float red[8];
  __shared__ float mv[2];
  int tid = threadIdx.x;
  float vals[4];
  float s = 0.f, ss = 0.f;
  for (int j = 0; j < 4; ++j) {
    float v = row[tid + 256 * j];
    vals[j] = v; s += v; ss += v * v;
  }
  for (int o = 32; o > 0; o >>= 1) { s += __shfl_down(s, o); ss += __shfl_down(ss, o); }
  int wid = tid >> 6, lane = tid & 63;
  if (lane == 0) { red[wid] = s; red[wid + 4] = ss; }
  __syncthreads();
  if (tid == 0) {
    float a = red[0] + red[1] + red[2] + red[3];
    float q = red[4] + red[5] + red[6] + red[7];
    float mean = a / (float)DD;
    float var = fmaxf(q / (float)DD - mean * mean, 0.f);
    mv[0] = mean; mv[1] = rsqrtf(var + 1e-5f);
  }
  __syncthreads();
  float mean = mv[0], rst = mv[1];
  unsigned short* drow = dst + (size_t)r * DD;
  for (int j = 0; j < 4; ++j) {
    int c = tid + 256 * j;
    float v = (vals[j] - mean) * rst * scale[c] + bias[c];
    drow[c] = f2bf(v);
  }
}

// ---------------- BT-form MFMA GEMM (m97 structure): acc = A[M,K] * W[N,K]^T ----------------
// linear LDS [128][32] + global_load_lds width 16, 2 barriers per K-step.
// EPI 0: Cb[row*N+col] = bf16(acc)                          (qkv)
// EPI 1: fout[row*DD+col] = xin[gidx[row]*DD+col] + acc     (x1 = x_sel + attn, f32)
// EPI 2: fout[gidx[row]*DD+col] = xin[row*DD+col] + acc     (scatter out = x1 + ffn, f32)
template <int EPI>
__launch_bounds__(256, 2)
__global__ void gemm_bt(const unsigned short* __restrict__ A,
                        const unsigned short* __restrict__ W,
                        int K, int N,
                        unsigned short* __restrict__ Cb,
                        const int* __restrict__ idx,
                        const float* __restrict__ xin,
                        float* __restrict__ fout) {
  __shared__ unsigned short As[128 * 32];
  __shared__ unsigned short Bs[128 * 32];
  int bm = blockIdx.x, bn = blockIdx.y;
  int tid = threadIdx.x;
  int wid = tid >> 6, lane = tid & 63;
  int quad = lane >> 4, l15 = lane & 15;
  int wm = (wid >> 1) * 64, wn = (wid & 1) * 64;

  f32x4 acc[4][4] = {};
  const int arow0 = bm * 128, brow0 = bn * 128;
  int srow = tid >> 2;
  int scol = (tid & 3) * 8;
  const unsigned short* Ag = A + (size_t)(arow0 + srow) * K + scol;
  const unsigned short* Wg = W + (size_t)(brow0 + srow) * K + scol;
  // wave-uniform LDS staging base: wave w covers rows 16w..16w+15 (1024B)
  unsigned short* AsW = As + (size_t)(tid & 192) * 8;
  unsigned short* BsW = Bs + (size_t)(tid & 192) * 8;

  for (int k0 = 0; k0 < K; k0 += 32) {
    __syncthreads();  // prior reads drained before overwrite
    gload16(Ag + k0, AsW);
    gload16(Ag + (size_t)64 * K + k0, AsW + 2048);
    gload16(Wg + k0, BsW);
    gload16(Wg + (size_t)64 * K + k0, BsW + 2048);
    __syncthreads();  // vmcnt(0) drain -> staged data visible
    short8 af[4], bfr[4];
    for (int t = 0; t < 4; ++t) af[t]  = *(const short8*)&As[(wm + t * 16 + l15) * 32 + quad * 8];
    for (int t = 0; t < 4; ++t) bfr[t] = *(const short8*)&Bs[(wn + t * 16 + l15) * 32 + quad * 8];
    for (int i = 0; i < 4; ++i)
      for (int j = 0; j < 4; ++j)
        acc[i][j] = __builtin_amdgcn_mfma_f32_16x16x32_bf16(af[i], bfr[j], acc[i][j], 0, 0, 0);
  }

  for (int i = 0; i < 4; ++i)
    for (int j = 0; j < 4; ++j)
      for (int r = 0; r < 4; ++r) {
        int row = arow0 + wm + i * 16 + quad * 4 + r;
        int col = brow0 + wn + j * 16 + l15;
        float v = acc[i][j][r];
        if (EPI == 0) {
          Cb[(size_t)row * N + col] = f2bf(v);
        } else if (EPI == 1) {
          int t = idx[row];
          fout[(size_t)row * DD + col] = xin[(size_t)t * DD + col] + v;
        } else {
          int t = idx[row];
          fout[(size_t)t * DD + col] = xin[(size_t)row * DD + col] + v;
        }
      }
}

// ---------------- dual-B GEMM for SwiGLU (m97 structure): g = silu(A*W1^T) * (A*W2^T) ----------------
__launch_bounds__(256, 2)
__global__ void gemm_dual(const unsigned short* __restrict__ A,
                          const unsigned short* __restrict__ W1,
                          const unsigned short* __restrict__ W2,
                          unsigned short* __restrict__ G,
                          int K, int N) {
  __shared__ unsigned short As[128 * 32];
  __shared__ unsigned short B1s[128 * 32];
  __shared__ unsigned short B2s[128 * 32];
  int bm = blockIdx.x, bn = blockIdx.y;
  int tid = threadIdx.x;
  int wid = tid >> 6, lane = tid & 63;
  int quad = lane >> 4, l15 = lane & 15;
  int wm = (wid >> 1) * 64, wn = (wid & 1) * 64;

  f32x4 acc1[4][4] = {};
  f32x4 acc2[4][4] = {};
  const int arow0 = bm * 128, brow0 = bn * 128;
  int srow = tid >> 2;
  int scol = (tid & 3) * 8;
  const unsigned short* Ag  = A  + (size_t)(arow0 + srow) * K + scol;
  const unsigned short* W1g = W1 + (size_t)(brow0 + srow) * K + scol;
  const unsigned short* W2g = W2 + (size_t)(brow0 + srow) * K + scol;
  unsigned short* AsW  = As  + (size_t)(tid & 192) * 8;
  unsigned short* B1sW = B1s + (size_t)(tid & 192) * 8;
  unsigned short* B2sW = B2s + (size_t)(tid & 192) * 8;

  for (int k0 = 0; k0 < K; k0 += 32) {
    __syncthreads();
    gload16(Ag + k0, AsW);
    gload16(Ag + (size_t)64 * K + k0, AsW + 2048);
    gload16(W1g + k0, B1sW);
    gload16(W1g + (size_t)64 * K + k0, B1sW + 2048);
    gload16(W2g + k0, B2sW);
    gload16(W2g + (size_t)64 * K + k0, B2sW + 2048);
    __syncthreads();
    short8 af[4], b1f[4], b2f[4];
    for (int t = 0; t < 4; ++t) af[t]  = *(const short8*)&As[(wm + t * 16 + l15) * 32 + quad * 8];
    for (int t = 0; t < 4; ++t) b1f[t] = *(const short8*)&B1s[(wn + t * 16 + l15) * 32 + quad * 8];
    for (int t = 0; t < 4; ++t) b2f[t] = *(const short8*)&B2s[(wn + t * 16 + l15) * 32 + quad * 8];
    for (int i = 0; i < 4; ++i)
      for (int j = 0; j < 4; ++j) {
        acc1[i][j] = __builtin_amdgcn_mfma_f32_16x16x32_bf16(af[i], b1f[j], acc1[i][j], 0, 0, 0);
        acc2[i][j] = __builtin_amdgcn_mfma_f32_16x16x32_bf16(af[i], b2f[j], acc2[i][j], 0, 0, 0);
      }
  }

  for (int i = 0; i < 4; ++i)
    for (int j = 0; j < 4; ++j)
      for (int r = 0; r < 4; ++r) {
        int row = arow0 + wm + i * 16 + quad * 4 + r;
        int col = brow0 + wn + j * 16 + l15;
        float u1 = acc1[i][j][r];
        float u2 = acc2[i][j][r];
        float sg = u1 / (1.0f + __expf(-u1));  // silu (native exp)
        G[(size_t)row * N + col] = f2bf(sg * u2);
      }
}

// ---------------- flash attention: QBLK=128, 8 waves, swapped-QK^T in-register softmax ----------------
// T14 async-STAGE: next K/V tile's global loads issued before current tile's compute.
// T5 setprio around MFMA clusters. exp2-domain online softmax with defer-max.
__launch_bounds__(512, 4)
__global__ void attn_kernel(const unsigned short* __restrict__ qkv_all,
                            unsigned short* __restrict__ obuf_all) {
  int qb = blockIdx.x;   // 0..15 (128 q-rows each)
  int h = blockIdx.y;    // 0..15
  const unsigned short* qkv = qkv_all + (size_t)blockIdx.z * KSEL * 3 * DD;
  unsigned short* obuf = obuf_all + (size_t)blockIdx.z * KSEL * DD;
  int tid = threadIdx.x, wid = tid >> 6, lane = tid & 63;
  int quad = lane >> 4, l15 = lane & 15;

  __shared__ unsigned short Ks[64][68];     // keys x dims
  __shared__ unsigned short Vt[64][68];     // V^T: dims x keys
  __shared__ unsigned short Ps[8][16][72];  // per-warp P: q-rows x keys (16B-aligned rows)

  const float SCL = 0.125f * 1.44269504f;   // scale * log2(e): exp2-domain softmax

  int qrow = qb * 128 + wid * 16 + l15;
  const unsigned short* qptr = qkv + (size_t)qrow * (3 * DD) + h * 64;
  short8 aq0 = *(const short8*)(qptr + quad * 8);
  short8 aq1 = *(const short8*)(qptr + 32 + quad * 8);

  float m_run = -1e30f, l_run = 0.f;        // per lane: q-row = l15 (raw-score domain)
  f32x4 o_acc[4] = {};

  int skey = tid >> 3;          // 0..63
  int scol = (tid & 7) * 8;     // 0..56
  const unsigned short* kbase = qkv + DD + h * 64 + (size_t)skey * (3 * DD) + scol;
  const unsigned short* vbase = qkv + 2 * DD + h * 64 + (size_t)skey * (3 * DD) + scol;

  const int NT = KSEL / 64;
  // prologue: tile 0 K/V -> regs
  uint4 kv = *(const uint4*)(kbase);
  uint4 vv = *(const uint4*)(vbase);

  for (int kt = 0; kt < NT; ++kt) {
    __syncthreads();  // prior tile's LDS reads complete
    *(uint4*)&Ks[skey][scol] = kv;
    {
      const unsigned short* vp = (const unsigned short*)&vv;
#pragma unroll
      for (int j = 0; j < 8; ++j) Vt[scol + j][skey] = vp[j];
    }
    __syncthreads();  // staged tile visible

    // T14: issue NEXT tile's loads now; latency hides under compute below
    if (kt + 1 < NT) {
      kv = *(const uint4*)(kbase + (size_t)(kt + 1) * 64 * (3 * DD));
      vv = *(const uint4*)(vbase + (size_t)(kt + 1) * 64 * (3 * DD));
    }

    // S^T: st[t][r] = score(key = 16t + 4*quad + r, q = l15)   (raw, unscaled)
    f32x4 st[4];
    __builtin_amdgcn_s_setprio(1);
#pragma unroll
    for (int t = 0; t < 4; ++t) {
      f32x4 z = {0.f, 0.f, 0.f, 0.f};
      short8 ka = *(const short8*)&Ks[t * 16 + l15][quad * 8];
      short8 kb = *(const short8*)&Ks[t * 16 + l15][32 + quad * 8];
      z = __builtin_amdgcn_mfma_f32_16x16x32_bf16(ka, aq0, z, 0, 0, 0);
      z = __builtin_amdgcn_mfma_f32_16x16x32_bf16(kb, aq1, z, 0, 0, 0);
      st[t] = z;
    }
    __builtin_amdgcn_s_setprio(0);

    // row max: 15 in-register + cross-quad (same l15 -> same q)
    float mx = fmaxf(fmaxf(st[0][0], st[0][1]), fmaxf(st[0][2], st[0][3]));
#pragma unroll
    for (int t = 1; t < 4; ++t)
      mx = fmaxf(mx, fmaxf(fmaxf(st[t][0], st[t][1]), fmaxf(st[t][2], st[t][3])));
    mx = fmaxf(mx, __shfl_xor(mx, 16));
    mx = fmaxf(mx, __shfl_xor(mx, 32));

    // defer-max: only rescale when max grew by > 64 raw (2^11.5 headroom in p)
    if (!__all(mx <= m_run + 64.0f)) {
      float mnew = fmaxf(m_run, mx);
      float alpha = exp2g((m_run - mnew) * SCL);
      float a0 = __shfl(alpha, quad * 4 + 0);
      float a1 = __shfl(alpha, quad * 4 + 1);
      float a2 = __shfl(alpha, quad * 4 + 2);
      float a3 = __shfl(alpha, quad * 4 + 3);
#pragma unroll
      for (int dt = 0; dt < 4; ++dt) {
        o_acc[dt][0] *= a0; o_acc[dt][1] *= a1;
        o_acc[dt][2] *= a2; o_acc[dt][3] *= a3;
      }
      l_run *= alpha;
      m_run = mnew;
    }

    float msc = m_run * SCL;
    float p[4][4];
    float ls = 0.f;
#pragma unroll
    for (int t = 0; t < 4; ++t)
#pragma unroll
      for (int r = 0; r < 4; ++r) {
        float e = exp2g(__builtin_fmaf(st[t][r], SCL, -msc));
        p[t][r] = e;
        ls += e;
      }
    ls += __shfl_xor(ls, 16);
    ls += __shfl_xor(ls, 32);
    l_run += ls;

    // P -> per-warp LDS (packed pairs; wave-local, no barrier needed)
#pragma unroll
    for (int t = 0; t < 4; ++t)
#pragma unroll
      for (int hh = 0; hh < 2; ++hh) {
        unsigned int w;
        asm("v_cvt_pk_bf16_f32 %0, %1, %2" : "=v"(w) : "v"(p[t][2 * hh]), "v"(p[t][2 * hh + 1]));
        *(unsigned int*)&Ps[wid][l15][t * 16 + quad * 4 + 2 * hh] = w;
      }

    short8 ap0 = *(const short8*)&Ps[wid][l15][quad * 8];
    short8 ap1 = *(const short8*)&Ps[wid][l15][32 + quad * 8];
    __builtin_amdgcn_s_setprio(1);
#pragma unroll
    for (int dt = 0; dt < 4; ++dt) {
      short8 vf0 = *(const short8*)&Vt[dt * 16 + l15][quad * 8];
      short8 vf1 = *(const short8*)&Vt[dt * 16 + l15][32 + quad * 8];
      o_acc[dt] = __builtin_amdgcn_mfma_f32_16x16x32_bf16(ap0, vf0, o_acc[dt], 0, 0, 0);
      o_acc[dt] = __builtin_amdgcn_mfma_f32_16x16x32_bf16(ap1, vf1, o_acc[dt], 0, 0, 0);
    }
    __builtin_amdgcn_s_setprio(0);
  }

  // epilogue: l for o_acc's rows (q = quad*4 + r) via shfl
  float rl[4];
#pragma unroll
  for (int r = 0; r < 4; ++r) rl[r] = 1.0f / __shfl(l_run, quad * 4 + r);
  int orow = qb * 128 + wid * 16 + quad * 4;
  unsigned short* op = obuf + h * 64;
#pragma unroll
  for (int dt = 0; dt < 4; ++dt)
#pragma unroll
    for (int r = 0; r < 4; ++r) {
      float v = o_acc[dt][r] * rl[r];
      op[(size_t)(orow + r) * DD + dt * 16 + l15] = f2bf(v);
    }
}

// ---------------- launch: batched across B with ws_size-adaptive chunking ----------------
extern "C" void kernel_launch(void* const* d_in, const int* in_sizes, int n_in,
                              void* d_out, int out_size, void* d_ws, size_t ws_size,
                              hipStream_t stream) {
  const float* x    = (const float*)d_in[0];
  const float* wr   = (const float*)d_in[1];
  const float* ln1s = (const float*)d_in[2];
  const float* ln1b = (const float*)d_in[3];
  const float* ln2s = (const float*)d_in[4];
  const float* ln2b = (const float*)d_in[5];
  const float* wqkv = (const float*)d_in[6];
  const float* wout = (const float*)d_in[7];
  const float* w1   = (const float*)d_in[8];
  const float* w2   = (const float*)d_in[9];
  const float* w3   = (const float*)d_in[10];
  float* out = (float*)d_out;
  char* ws = (char*)d_ws;

  // control region [0, 1 MiB)
  double* dots  = (double*)(ws + 0);        // 128 KiB
  float*  sig   = (float*)(ws + 131072);    // 64 KiB
  int*    flags = (int*)(ws + 196608);      // 64 KiB
  int*    idx   = (int*)(ws + 262144);      // 32 KiB (global token indices)
  float*  means = (float*)(ws + 294912);    // 16 B
  // bf16 weight copies [1 MiB, 33 MiB)
  unsigned short* wqkv_h = (unsigned short*)(ws + ((size_t)1 << 20));   // 6 MiB
  unsigned short* wout_h = (unsigned short*)(ws + ((size_t)7 << 20));   // 2 MiB
  unsigned short* w1_h   = (unsigned short*)(ws + ((size_t)9 << 20));   // 8 MiB
  unsigned short* w2_h   = (unsigned short*)(ws + ((size_t)17 << 20));  // 8 MiB
  unsigned short* w3_h   = (unsigned short*)(ws + ((size_t)25 << 20));  // 8 MiB
  const size_t base = (size_t)33 << 20;

  // out = x (pass-through for unselected tokens), f32, 64 MiB
  hipMemcpyAsync(out, x, (size_t)BB * TT * DD * sizeof(float),
                 hipMemcpyDeviceToDevice, stream);

  // merged weight conversion f32 -> bf16 (16M elements, 4/thread)
  cvt_all_kernel<<<dim3(16 * 1024 * 1024 / 1024), dim3(256), 0, stream>>>(
      wqkv, wout, w1, w2, w3, wqkv_h, wout_h, w1_h, w2_h, w3_h);

  router_kernel<<<dim3(BB * TT / 4), dim3(256), 0, stream>>>(x, wr, dots, sig);
  rank_kernel<<<dim3(BB * 16), dim3(256), 0, stream>>>(dots, flags);
  compact_kernel<<<dim3(BB), dim3(256), 0, stream>>>(flags, sig, idx, means);
  aux_kernel<<<dim3(1), dim3(64), 0, stream>>>(means, out + (size_t)BB * TT * DD);

  // per-row buffer bytes: x1 4096 + norm 2048 + max(qkv 6144 + obuf 2048, gbuf 8192) = 14336
  int cb = 4;  // batches per chunk
  while (cb > 1 && base + (size_t)cb * KSEL * 14336 > ws_size) cb >>= 1;

  for (int c0 = 0; c0 < BB; c0 += cb) {
    const int R = cb * KSEL;  // rows in this chunk
    const int* gidx = idx + (size_t)c0 * KSEL;
    float*          x1    = (float*)(ws + base);
    unsigned short* normb = (unsigned short*)(ws + base + (size_t)R * 4096);
    unsigned short* qkvb  = (unsigned short*)(ws + base + (size_t)R * 6144);
    unsigned short* obufb = (unsigned short*)(ws + base + (size_t)R * 12288);
    unsigned short* gbuf  = qkvb;  // overlays dead qkv+obuf (R*8192 <= R*6144 + R*2048)

    // ln1 on gathered selected tokens -> bf16
    ln_kernel<<<dim3(R), dim3(256), 0, stream>>>(x, gidx, ln1s, ln1b, normb);

    // qkv = normed @ w_qkv^T  (R x 3072, K=1024) -> bf16
    gemm_bt<0><<<dim3(R / 128, 3 * DD / 128), dim3(256), 0, stream>>>(
        normb, wqkv_h, DD, 3 * DD, qkvb, nullptr, nullptr, nullptr);

    // attention -> bf16 obuf (per-batch via blockIdx.z)
    attn_kernel<<<dim3(KSEL / 128, HH, cb), dim3(512), 0, stream>>>(qkvb, obufb);

    // x1 = x_sel + o @ w_out^T  -> f32
    gemm_bt<1><<<dim3(R / 128, DD / 128), dim3(256), 0, stream>>>(
        obufb, wout_h, DD, DD, nullptr, gidx, x, x1);

    // ln2 -> bf16
    ln_kernel<<<dim3(R), dim3(256), 0, stream>>>(x1, nullptr, ln2s, ln2b, normb);

    // g = silu(h@w1^T) * (h@w2^T)  (R x 4096, K=1024) -> bf16
    gemm_dual<<<dim3(R / 128, DFF / 128), dim3(256), 0, stream>>>(
        normb, w1_h, w2_h, gbuf, DD, DFF);

    // out[gidx, :] = x1 + g @ w3^T  (K=4096) -> f32 scatter
    gemm_bt<2><<<dim3(R / 128, DD / 128), dim3(256), 0, stream>>>(
        gbuf, w3_h, DFF, DD, nullptr, gidx, x1, out);
  }
}

// Round 6
// 802.851 us; speedup vs baseline: 1.9628x; 1.0016x over previous
//
#include <hip/hip_runtime.h>
#include <hip/hip_bf16.h>
#include <math.h>

#define BB 4
#define TT 4096
#define DD 1024
#define HH 16
#define DFF 4096
#define KSEL 2048

typedef __attribute__((ext_vector_type(8))) short short8;
typedef __attribute__((ext_vector_type(4))) float f32x4;

__device__ __forceinline__ unsigned short f2bf(float f) {
  union { float f; unsigned int i; } v; v.f = f;
  unsigned int x = v.i;
  unsigned int r = (x + 0x7fffu + ((x >> 16) & 1u)) >> 16;
  return (unsigned short)r;
}
__device__ __forceinline__ float bf2f(unsigned short u) {
  union { unsigned int i; float f; } v; v.i = ((unsigned int)u) << 16; return v.f;
}

// native 2^x (v_exp_f32) — avoids glibc __exp2f macro collision
__device__ __forceinline__ float exp2g(float x) { return __builtin_amdgcn_exp2f(x); }

// async global->LDS, 16B per lane; lds ptr must be wave-uniform (lane0 = wave base)
__device__ __forceinline__ void gload16(const void* g, void* l) {
  __builtin_amdgcn_global_load_lds(
      (const __attribute__((address_space(1))) void*)g,
      (__attribute__((address_space(3))) void*)l,
      16, 0, 0);
}

// ---------------- merged f32 -> bf16 conversion for all 5 weight tensors ----------------
__global__ void cvt_all_kernel(const float* __restrict__ s0, const float* __restrict__ s1,
                               const float* __restrict__ s2, const float* __restrict__ s3,
                               const float* __restrict__ s4,
                               unsigned short* __restrict__ d0, unsigned short* __restrict__ d1,
                               unsigned short* __restrict__ d2, unsigned short* __restrict__ d3,
                               unsigned short* __restrict__ d4) {
  const long n0 = (long)3 * DD * DD;     // wqkv  3M
  const long n1 = (long)DD * DD;         // wout  1M
  const long n2 = (long)DFF * DD;        // w1/w2/w3  4M each
  long i = ((long)blockIdx.x * 256 + threadIdx.x) * 4;
  const float* src; unsigned short* dst; long off;
  if (i < n0)                    { src = s0; dst = d0; off = i; }
  else if (i < n0 + n1)          { src = s1; dst = d1; off = i - n0; }
  else if (i < n0 + n1 + n2)     { src = s2; dst = d2; off = i - n0 - n1; }
  else if (i < n0 + n1 + 2*n2)   { src = s3; dst = d3; off = i - n0 - n1 - n2; }
  else                           { src = s4; dst = d4; off = i - n0 - n1 - 2*n2; }
  float4 v = *(const float4*)(src + off);
  ushort4 o;
  o.x = f2bf(v.x); o.y = f2bf(v.y); o.z = f2bf(v.z); o.w = f2bf(v.w);
  *(ushort4*)(dst + off) = o;
}

// ---------------- router: f64 dot per token + sigmoid ----------------
__global__ void router_kernel(const float* __restrict__ x,
                              const float* __restrict__ wr,
                              double* __restrict__ dots, float* __restrict__ sig) {
  int token = blockIdx.x * 4 + (threadIdx.x >> 6);
  int lane = threadIdx.x & 63;
  const float* xr = x + (size_t)token * DD;
  double s = 0.0;
  for (int j = lane; j < DD; j += 64)
    s += (double)xr[j] * (double)wr[j];
  for (int o = 32; o > 0; o >>= 1) s += __shfl_down(s, o);
  if (lane == 0) {
    dots[token] = s;
    sig[token] = 1.0f / (1.0f + expf((float)(-s)));
  }
}

// ---------------- rank: count tokens strictly ahead; flag top-k ----------------
__global__ void rank_kernel(const double* __restrict__ dots, int* __restrict__ flags) {
  __shared__ double sd[TT];
  int b = blockIdx.x >> 4;
  int chunk = blockIdx.x & 15;
  const double* drow = dots + (size_t)b * TT;
  for (int j = threadIdx.x; j < TT; j += 256) sd[j] = drow[j];
  __syncthreads();
  int i = chunk * 256 + threadIdx.x;
  double di = sd[i];
  int cnt = 0;
  for (int j = 0; j < TT; ++j) {
    double dj = sd[j];
    cnt += (int)((dj > di) || (dj == di && j < i));
  }
  flags[(size_t)b * TT + i] = (cnt < KSEL) ? 1 : 0;
}

// ---------------- compact: ascending selected GLOBAL indices (b*TT+t) + batch mean ----------------
__global__ void compact_kernel(const int* __restrict__ flags, const float* __restrict__ sig,
                               int* __restrict__ idx, float* __restrict__ means) {
  __shared__ int part[256];
  __shared__ float ssum[256];
  int b = blockIdx.x;
  const int* f = flags + (size_t)b * TT;
  int tid = threadIdx.x;
  int local = 0; float fs = 0.f;
  for (int j = 0; j < 16; ++j) {
    local += f[tid * 16 + j];
    fs += sig[(size_t)b * TT + tid * 16 + j];
  }
  part[tid] = local; ssum[tid] = fs;
  __syncthreads();
  if (tid == 0) {
    int run = 0;
    for (int t = 0; t < 256; ++t) { int c = part[t]; part[t] = run; run += c; }
    float tot = 0.f;
    for (int t = 0; t < 256; ++t) tot += ssum[t];
    means[b] = tot / (float)TT;
  }
  __syncthreads();
  int pos = part[tid];
  for (int j = 0; j < 16; ++j) {
    int t = tid * 16 + j;
    if (f[t]) { idx[(size_t)b * KSEL + pos] = b * TT + t; ++pos; }
  }
}

__global__ void aux_kernel(const float* __restrict__ means, float* __restrict__ out_aux) {
  if (threadIdx.x == 0 && blockIdx.x == 0) {
    float m = 0.f;
    for (int b = 0; b < BB; ++b) m += means[b];
    m *= (1.0f / BB);
    float v = 0.f;
    for (int b = 0; b < BB; ++b) { float d = means[b] - m; v += d * d; }
    v /= (float)(BB - 1);
    *out_aux = v;
  }
}

// ---------------- layernorm: f32 src (optional gather via GLOBAL idx), bf16 dst ----------------
__global__ void ln_kernel(const float* __restrict__ src,
                          const int* __restrict__ idx,
                          const float* __restrict__ scale,
                          const float* __restrict__ bias,
                          unsigned short* __restrict__ dst) {
  int r = blockIdx.x;
  const float* row;
  if (idx) {
    int t = idx[r];                 // global token index b*TT + t
    row = src + (size_t)t * DD;
  } else {
    row = src + (size_t)r * DD;
  }
  __shared__ float red[8];
  __shared__ float mv[2];
  int tid = threadIdx.x;
  float vals[4];
  float s = 0.f, ss = 0.f;
  for (int j = 0; j < 4; ++j) {
    float v = row[tid + 256 * j];
    vals[j] = v; s += v; ss += v * v;
  }
  for (int o = 32; o > 0; o >>= 1) { s += __shfl_down(s, o); ss += __shfl_down(ss, o); }
  int wid = tid >> 6, lane = tid & 63;
  if (lane == 0) { red[wid] = s; red[wid + 4] = ss; }
  __syncthreads();
  if (tid == 0) {
    float a = red[0] + red[1] + red[2] + red[3];
    float q = red[4] + red[5] + red[6] + red[7];
    float mean = a / (float)DD;
    float var = fmaxf(q / (float)DD - mean * mean, 0.f);
    mv[0] = mean; mv[1] = rsqrtf(var + 1e-5f);
  }
  __syncthreads();
  float mean = mv[0], rst = mv[1];
  unsigned short* drow = dst + (size_t)r * DD;
  for (int j = 0; j < 4; ++j) {
    int c = tid + 256 * j;
    float v = (vals[j] - mean) * rst * scale[c] + bias[c];
    drow[c] = f2bf(v);
  }
}

// ---------------- BT-form MFMA GEMM (m97 structure): acc = A[M,K] * W[N,K]^T ----------------
// linear LDS [128][32] + global_load_lds width 16, 2 barriers per K-step.
// EPI 0: Cb[row*N+col] = bf16(acc)                          (qkv)
// EPI 1: fout[row*DD+col] = xin[gidx[row]*DD+col] + acc     (x1 = x_sel + attn, f32)
// EPI 2: fout[gidx[row]*DD+col] = xin[row*DD+col] + acc     (scatter out = x1 + ffn, f32)
template <int EPI>
__launch_bounds__(256, 2)
__global__ void gemm_bt(const unsigned short* __restrict__ A,
                        const unsigned short* __restrict__ W,
                        int K, int N,
                        unsigned short* __restrict__ Cb,
                        const int* __restrict__ idx,
                        const float* __restrict__ xin,
                        float* __restrict__ fout) {
  __shared__ unsigned short As[128 * 32];
  __shared__ unsigned short Bs[128 * 32];
  int bm = blockIdx.x, bn = blockIdx.y;
  int tid = threadIdx.x;
  int wid = tid >> 6, lane = tid & 63;
  int quad = lane >> 4, l15 = lane & 15;
  int wm = (wid >> 1) * 64, wn = (wid & 1) * 64;

  f32x4 acc[4][4] = {};
  const int arow0 = bm * 128, brow0 = bn * 128;
  int srow = tid >> 2;
  int scol = (tid & 3) * 8;
  const unsigned short* Ag = A + (size_t)(arow0 + srow) * K + scol;
  const unsigned short* Wg = W + (size_t)(brow0 + srow) * K + scol;
  // wave-uniform LDS staging base: wave w covers rows 16w..16w+15 (1024B)
  unsigned short* AsW = As + (size_t)(tid & 192) * 8;
  unsigned short* BsW = Bs + (size_t)(tid & 192) * 8;

  for (int k0 = 0; k0 < K; k0 += 32) {
    __syncthreads();  // prior reads drained before overwrite
    gload16(Ag + k0, AsW);
    gload16(Ag + (size_t)64 * K + k0, AsW + 2048);
    gload16(Wg + k0, BsW);
    gload16(Wg + (size_t)64 * K + k0, BsW + 2048);
    __syncthreads();  // vmcnt(0) drain -> staged data visible
    short8 af[4], bfr[4];
    for (int t = 0; t < 4; ++t) af[t]  = *(const short8*)&As[(wm + t * 16 + l15) * 32 + quad * 8];
    for (int t = 0; t < 4; ++t) bfr[t] = *(const short8*)&Bs[(wn + t * 16 + l15) * 32 + quad * 8];
    for (int i = 0; i < 4; ++i)
      for (int j = 0; j < 4; ++j)
        acc[i][j] = __builtin_amdgcn_mfma_f32_16x16x32_bf16(af[i], bfr[j], acc[i][j], 0, 0, 0);
  }

  for (int i = 0; i < 4; ++i)
    for (int j = 0; j < 4; ++j)
      for (int r = 0; r < 4; ++r) {
        int row = arow0 + wm + i * 16 + quad * 4 + r;
        int col = brow0 + wn + j * 16 + l15;
        float v = acc[i][j][r];
        if (EPI == 0) {
          Cb[(size_t)row * N + col] = f2bf(v);
        } else if (EPI == 1) {
          int t = idx[row];
          fout[(size_t)row * DD + col] = xin[(size_t)t * DD + col] + v;
        } else {
          int t = idx[row];
          fout[(size_t)t * DD + col] = xin[(size_t)row * DD + col] + v;
        }
      }
}

// ---------------- dual-B GEMM for SwiGLU (m97 structure): g = silu(A*W1^T) * (A*W2^T) ----------------
__launch_bounds__(256, 2)
__global__ void gemm_dual(const unsigned short* __restrict__ A,
                          const unsigned short* __restrict__ W1,
                          const unsigned short* __restrict__ W2,
                          unsigned short* __restrict__ G,
                          int K, int N) {
  __shared__ unsigned short As[128 * 32];
  __shared__ unsigned short B1s[128 * 32];
  __shared__ unsigned short B2s[128 * 32];
  int bm = blockIdx.x, bn = blockIdx.y;
  int tid = threadIdx.x;
  int wid = tid >> 6, lane = tid & 63;
  int quad = lane >> 4, l15 = lane & 15;
  int wm = (wid >> 1) * 64, wn = (wid & 1) * 64;

  f32x4 acc1[4][4] = {};
  f32x4 acc2[4][4] = {};
  const int arow0 = bm * 128, brow0 = bn * 128;
  int srow = tid >> 2;
  int scol = (tid & 3) * 8;
  const unsigned short* Ag  = A  + (size_t)(arow0 + srow) * K + scol;
  const unsigned short* W1g = W1 + (size_t)(brow0 + srow) * K + scol;
  const unsigned short* W2g = W2 + (size_t)(brow0 + srow) * K + scol;
  unsigned short* AsW  = As  + (size_t)(tid & 192) * 8;
  unsigned short* B1sW = B1s + (size_t)(tid & 192) * 8;
  unsigned short* B2sW = B2s + (size_t)(tid & 192) * 8;

  for (int k0 = 0; k0 < K; k0 += 32) {
    __syncthreads();
    gload16(Ag + k0, AsW);
    gload16(Ag + (size_t)64 * K + k0, AsW + 2048);
    gload16(W1g + k0, B1sW);
    gload16(W1g + (size_t)64 * K + k0, B1sW + 2048);
    gload16(W2g + k0, B2sW);
    gload16(W2g + (size_t)64 * K + k0, B2sW + 2048);
    __syncthreads();
    short8 af[4], b1f[4], b2f[4];
    for (int t = 0; t < 4; ++t) af[t]  = *(const short8*)&As[(wm + t * 16 + l15) * 32 + quad * 8];
    for (int t = 0; t < 4; ++t) b1f[t] = *(const short8*)&B1s[(wn + t * 16 + l15) * 32 + quad * 8];
    for (int t = 0; t < 4; ++t) b2f[t] = *(const short8*)&B2s[(wn + t * 16 + l15) * 32 + quad * 8];
    for (int i = 0; i < 4; ++i)
      for (int j = 0; j < 4; ++j) {
        acc1[i][j] = __builtin_amdgcn_mfma_f32_16x16x32_bf16(af[i], b1f[j], acc1[i][j], 0, 0, 0);
        acc2[i][j] = __builtin_amdgcn_mfma_f32_16x16x32_bf16(af[i], b2f[j], acc2[i][j], 0, 0, 0);
      }
  }

  for (int i = 0; i < 4; ++i)
    for (int j = 0; j < 4; ++j)
      for (int r = 0; r < 4; ++r) {
        int row = arow0 + wm + i * 16 + quad * 4 + r;
        int col = brow0 + wn + j * 16 + l15;
        float u1 = acc1[i][j][r];
        float u2 = acc2[i][j][r];
        float sg = u1 / (1.0f + __expf(-u1));  // silu (native exp)
        G[(size_t)row * N + col] = f2bf(sg * u2);
      }
}

// ---------------- flash attention: 4 waves x 32 q-rows (2 q-frags), swapped-QK^T ----------------
// 2 q-frags per wave halve LDS fragment reads per MFMA (K/V frags amortized over 2x q).
// T14 prefetch, T5 setprio, exp2-domain online softmax with defer-max.
__launch_bounds__(256)
__global__ void attn_kernel(const unsigned short* __restrict__ qkv_all,
                            unsigned short* __restrict__ obuf_all) {
  int qb = blockIdx.x;   // 0..15 (128 q-rows each)
  int h = blockIdx.y;    // 0..15
  const unsigned short* qkv = qkv_all + (size_t)blockIdx.z * KSEL * 3 * DD;
  unsigned short* obuf = obuf_all + (size_t)blockIdx.z * KSEL * DD;
  int tid = threadIdx.x, wid = tid >> 6, lane = tid & 63;
  int quad = lane >> 4, l15 = lane & 15;

  __shared__ unsigned short Ks[64][68];        // keys x dims
  __shared__ unsigned short Vt[64][68];        // V^T: dims x keys
  __shared__ unsigned short Ps[4][2][16][72];  // per-warp, per-q-frag P tiles

  const float SCL = 0.125f * 1.44269504f;   // scale * log2(e): exp2-domain softmax

  // per-wave 32 q-rows: frag g covers q = qb*128 + wid*32 + g*16 + l15
  short8 aq0[2], aq1[2];
#pragma unroll
  for (int g = 0; g < 2; ++g) {
    int qrow = qb * 128 + wid * 32 + g * 16 + l15;
    const unsigned short* qptr = qkv + (size_t)qrow * (3 * DD) + h * 64;
    aq0[g] = *(const short8*)(qptr + quad * 8);
    aq1[g] = *(const short8*)(qptr + 32 + quad * 8);
  }

  float m_run[2] = {-1e30f, -1e30f}, l_run[2] = {0.f, 0.f};
  f32x4 o_acc[2][4] = {};

  // staging: 256 threads cover 64 keys x 64 dims (2 x uint4 per thread per matrix)
  int skey = tid >> 2;               // 0..63
  int scol = (tid & 3) * 16;         // 0,16,32,48
  const unsigned short* kbase = qkv + DD + h * 64 + (size_t)skey * (3 * DD) + scol;
  const unsigned short* vbase = qkv + 2 * DD + h * 64 + (size_t)skey * (3 * DD) + scol;

  const int NT = KSEL / 64;
  // prologue: tile 0 K/V -> regs
  uint4 kv0 = *(const uint4*)(kbase);
  uint4 kv1 = *(const uint4*)(kbase + 8);
  uint4 vv0 = *(const uint4*)(vbase);
  uint4 vv1 = *(const uint4*)(vbase + 8);

  for (int kt = 0; kt < NT; ++kt) {
    __syncthreads();  // prior tile's LDS reads complete
    *(uint4*)&Ks[skey][scol] = kv0;
    *(uint4*)&Ks[skey][scol + 8] = kv1;
    {
      const unsigned short* vp0 = (const unsigned short*)&vv0;
      const unsigned short* vp1 = (const unsigned short*)&vv1;
#pragma unroll
      for (int j = 0; j < 8; ++j) Vt[scol + j][skey] = vp0[j];
#pragma unroll
      for (int j = 0; j < 8; ++j) Vt[scol + 8 + j][skey] = vp1[j];
    }
    __syncthreads();  // staged tile visible

    // T14: issue NEXT tile's loads now; latency hides under compute below
    if (kt + 1 < NT) {
      size_t off = (size_t)(kt + 1) * 64 * (3 * DD);
      kv0 = *(const uint4*)(kbase + off);
      kv1 = *(const uint4*)(kbase + off + 8);
      vv0 = *(const uint4*)(vbase + off);
      vv1 = *(const uint4*)(vbase + off + 8);
    }

    // S^T: st[g][t][r] = score(key = 16t + 4*quad + r, q = frag g row l15)
    f32x4 st[2][4];
    __builtin_amdgcn_s_setprio(1);
#pragma unroll
    for (int t = 0; t < 4; ++t) {
      short8 ka = *(const short8*)&Ks[t * 16 + l15][quad * 8];
      short8 kb = *(const short8*)&Ks[t * 16 + l15][32 + quad * 8];
#pragma unroll
      for (int g = 0; g < 2; ++g) {
        f32x4 z = {0.f, 0.f, 0.f, 0.f};
        z = __builtin_amdgcn_mfma_f32_16x16x32_bf16(ka, aq0[g], z, 0, 0, 0);
        z = __builtin_amdgcn_mfma_f32_16x16x32_bf16(kb, aq1[g], z, 0, 0, 0);
        st[g][t] = z;
      }
    }
    __builtin_amdgcn_s_setprio(0);

    // row max per frag: 15 in-register + cross-quad (same l15 -> same q)
    float mx[2];
#pragma unroll
    for (int g = 0; g < 2; ++g) {
      float m = fmaxf(fmaxf(st[g][0][0], st[g][0][1]), fmaxf(st[g][0][2], st[g][0][3]));
#pragma unroll
      for (int t = 1; t < 4; ++t)
        m = fmaxf(m, fmaxf(fmaxf(st[g][t][0], st[g][t][1]), fmaxf(st[g][t][2], st[g][t][3])));
      m = fmaxf(m, __shfl_xor(m, 16));
      m = fmaxf(m, __shfl_xor(m, 32));
      mx[g] = m;
    }

    // defer-max: rescale only when either frag's max grew by > 64 raw
    bool ok = (mx[0] <= m_run[0] + 64.0f) && (mx[1] <= m_run[1] + 64.0f);
    if (!__all(ok)) {
#pragma unroll
      for (int g = 0; g < 2; ++g) {
        float mnew = fmaxf(m_run[g], mx[g]);
        float alpha = exp2g((m_run[g] - mnew) * SCL);
        float a0 = __shfl(alpha, quad * 4 + 0);
        float a1 = __shfl(alpha, quad * 4 + 1);
        float a2 = __shfl(alpha, quad * 4 + 2);
        float a3 = __shfl(alpha, quad * 4 + 3);
#pragma unroll
        for (int dt = 0; dt < 4; ++dt) {
          o_acc[g][dt][0] *= a0; o_acc[g][dt][1] *= a1;
          o_acc[g][dt][2] *= a2; o_acc[g][dt][3] *= a3;
        }
        l_run[g] *= alpha;
        m_run[g] = mnew;
      }
    }

    // exp + row-sum + P->LDS per frag (packed pairs; wave-local, no barrier)
#pragma unroll
    for (int g = 0; g < 2; ++g) {
      float msc = m_run[g] * SCL;
      float ls = 0.f;
#pragma unroll
      for (int t = 0; t < 4; ++t) {
        float p0 = exp2g(__builtin_fmaf(st[g][t][0], SCL, -msc));
        float p1 = exp2g(__builtin_fmaf(st[g][t][1], SCL, -msc));
        float p2 = exp2g(__builtin_fmaf(st[g][t][2], SCL, -msc));
        float p3 = exp2g(__builtin_fmaf(st[g][t][3], SCL, -msc));
        ls += (p0 + p1) + (p2 + p3);
        unsigned int w0, w1;
        asm("v_cvt_pk_bf16_f32 %0, %1, %2" : "=v"(w0) : "v"(p0), "v"(p1));
        asm("v_cvt_pk_bf16_f32 %0, %1, %2" : "=v"(w1) : "v"(p2), "v"(p3));
        *(unsigned int*)&Ps[wid][g][l15][t * 16 + quad * 4] = w0;
        *(unsigned int*)&Ps[wid][g][l15][t * 16 + quad * 4 + 2] = w1;
      }
      ls += __shfl_xor(ls, 16);
      ls += __shfl_xor(ls, 32);
      l_run[g] += ls;
    }

    // PV: V-frags read once, used by both q-frags
    short8 ap0[2], ap1[2];
#pragma unroll
    for (int g = 0; g < 2; ++g) {
      ap0[g] = *(const short8*)&Ps[wid][g][l15][quad * 8];
      ap1[g] = *(const short8*)&Ps[wid][g][l15][32 + quad * 8];
    }
    __builtin_amdgcn_s_setprio(1);
#pragma unroll
    for (int dt = 0; dt < 4; ++dt) {
      short8 vf0 = *(const short8*)&Vt[dt * 16 + l15][quad * 8];
      short8 vf1 = *(const short8*)&Vt[dt * 16 + l15][32 + quad * 8];
#pragma unroll
      for (int g = 0; g < 2; ++g) {
        o_acc[g][dt] = __builtin_amdgcn_mfma_f32_16x16x32_bf16(ap0[g], vf0, o_acc[g][dt], 0, 0, 0);
        o_acc[g][dt] = __builtin_amdgcn_mfma_f32_16x16x32_bf16(ap1[g], vf1, o_acc[g][dt], 0, 0, 0);
      }
    }
    __builtin_amdgcn_s_setprio(0);
  }

  // epilogue per frag: l for o_acc's rows (q = quad*4 + r) via shfl
  unsigned short* op = obuf + h * 64;
#pragma unroll
  for (int g = 0; g < 2; ++g) {
    float rl[4];
#pragma unroll
    for (int r = 0; r < 4; ++r) rl[r] = 1.0f / __shfl(l_run[g], quad * 4 + r);
    int orow = qb * 128 + wid * 32 + g * 16 + quad * 4;
#pragma unroll
    for (int dt = 0; dt < 4; ++dt)
#pragma unroll
      for (int r = 0; r < 4; ++r) {
        float v = o_acc[g][dt][r] * rl[r];
        op[(size_t)(orow + r) * DD + dt * 16 + l15] = f2bf(v);
      }
  }
}

// ---------------- launch: batched across B with ws_size-adaptive chunking ----------------
extern "C" void kernel_launch(void* const* d_in, const int* in_sizes, int n_in,
                              void* d_out, int out_size, void* d_ws, size_t ws_size,
                              hipStream_t stream) {
  const float* x    = (const float*)d_in[0];
  const float* wr   = (const float*)d_in[1];
  const float* ln1s = (const float*)d_in[2];
  const float* ln1b = (const float*)d_in[3];
  const float* ln2s = (const float*)d_in[4];
  const float* ln2b = (const float*)d_in[5];
  const float* wqkv = (const float*)d_in[6];
  const float* wout = (const float*)d_in[7];
  const float* w1   = (const float*)d_in[8];
  const float* w2   = (const float*)d_in[9];
  const float* w3   = (const float*)d_in[10];
  float* out = (float*)d_out;
  char* ws = (char*)d_ws;

  // control region [0, 1 MiB)
  double* dots  = (double*)(ws + 0);        // 128 KiB
  float*  sig   = (float*)(ws + 131072);    // 64 KiB
  int*    flags = (int*)(ws + 196608);      // 64 KiB
  int*    idx   = (int*)(ws + 262144);      // 32 KiB (global token indices)
  float*  means = (float*)(ws + 294912);    // 16 B
  // bf16 weight copies [1 MiB, 33 MiB)
  unsigned short* wqkv_h = (unsigned short*)(ws + ((size_t)1 << 20));   // 6 MiB
  unsigned short* wout_h = (unsigned short*)(ws + ((size_t)7 << 20));   // 2 MiB
  unsigned short* w1_h   = (unsigned short*)(ws + ((size_t)9 << 20));   // 8 MiB
  unsigned short* w2_h   = (unsigned short*)(ws + ((size_t)17 << 20));  // 8 MiB
  unsigned short* w3_h   = (unsigned short*)(ws + ((size_t)25 << 20));  // 8 MiB
  const size_t base = (size_t)33 << 20;

  // out = x (pass-through for unselected tokens), f32, 64 MiB
  hipMemcpyAsync(out, x, (size_t)BB * TT * DD * sizeof(float),
                 hipMemcpyDeviceToDevice, stream);

  // merged weight conversion f32 -> bf16 (16M elements, 4/thread)
  cvt_all_kernel<<<dim3(16 * 1024 * 1024 / 1024), dim3(256), 0, stream>>>(
      wqkv, wout, w1, w2, w3, wqkv_h, wout_h, w1_h, w2_h, w3_h);

  router_kernel<<<dim3(BB * TT / 4), dim3(256), 0, stream>>>(x, wr, dots, sig);
  rank_kernel<<<dim3(BB * 16), dim3(256), 0, stream>>>(dots, flags);
  compact_kernel<<<dim3(BB), dim3(256), 0, stream>>>(flags, sig, idx, means);
  aux_kernel<<<dim3(1), dim3(64), 0, stream>>>(means, out + (size_t)BB * TT * DD);

  // per-row buffer bytes: x1 4096 + norm 2048 + max(qkv 6144 + obuf 2048, gbuf 8192) = 14336
  int cb = 4;  // batches per chunk
  while (cb > 1 && base + (size_t)cb * KSEL * 14336 > ws_size) cb >>= 1;

  for (int c0 = 0; c0 < BB; c0 += cb) {
    const int R = cb * KSEL;  // rows in this chunk
    const int* gidx = idx + (size_t)c0 * KSEL;
    float*          x1    = (float*)(ws + base);
    unsigned short* normb = (unsigned short*)(ws + base + (size_t)R * 4096);
    unsigned short* qkvb  = (unsigned short*)(ws + base + (size_t)R * 6144);
    unsigned short* obufb = (unsigned short*)(ws + base + (size_t)R * 12288);
    unsigned short* gbuf  = qkvb;  // overlays dead qkv+obuf (R*8192 <= R*6144 + R*2048)

    // ln1 on gathered selected tokens -> bf16
    ln_kernel<<<dim3(R), dim3(256), 0, stream>>>(x, gidx, ln1s, ln1b, normb);

    // qkv = normed @ w_qkv^T  (R x 3072, K=1024) -> bf16
    gemm_bt<0><<<dim3(R / 128, 3 * DD / 128), dim3(256), 0, stream>>>(
        normb, wqkv_h, DD, 3 * DD, qkvb, nullptr, nullptr, nullptr);

    // attention -> bf16 obuf (per-batch via blockIdx.z)
    attn_kernel<<<dim3(KSEL / 128, HH, cb), dim3(256), 0, stream>>>(qkvb, obufb);

    // x1 = x_sel + o @ w_out^T  -> f32
    gemm_bt<1><<<dim3(R / 128, DD / 128), dim3(256), 0, stream>>>(
        obufb, wout_h, DD, DD, nullptr, gidx, x, x1);

    // ln2 -> bf16
    ln_kernel<<<dim3(R), dim3(256), 0, stream>>>(x1, nullptr, ln2s, ln2b, normb);

    // g = silu(h@w1^T) * (h@w2^T)  (R x 4096, K=1024) -> bf16
    gemm_dual<<<dim3(R / 128, DFF / 128), dim3(256), 0, stream>>>(
        normb, w1_h, w2_h, gbuf, DD, DFF);

    // out[gidx, :] = x1 + g @ w3^T  (K=4096) -> f32 scatter
    gemm_bt<2><<<dim3(R / 128, DD / 128), dim3(256), 0, stream>>>(
        gbuf, w3_h, DFF, DD, nullptr, gidx, x1, out);
  }
}